// Round 9
// baseline (174.342 us; speedup 1.0000x reference)
//
#include <hip/hip_runtime.h>
#include <hip/hip_bf16.h>
#include <stdint.h>

#define DEV __device__ __forceinline__

typedef __attribute__((ext_vector_type(8))) short short8;   // 8 bf16 (4 VGPRs)
typedef __attribute__((ext_vector_type(4))) float f32x4;    // MFMA acc

#define TWO_LOG2E 2.8853900817779268f   // 2*log2(e): exp(2x) == exp2(x*TWO_LOG2E)

// ---------------------------------------------------------------- helpers
DEV unsigned short f2bf(float f) {           // fp32 -> bf16, RNE
  uint32_t u = __float_as_uint(f);
  u += 0x7FFFu + ((u >> 16) & 1u);
  return (unsigned short)(u >> 16);
}

DEV uint2 pk4(float4 f) {                    // 4 fp32 -> 4 bf16 (packed cvt)
  union { __hip_bfloat162 h; unsigned u; } a, b;
  a.h = __float22bfloat162_rn(make_float2(f.x, f.y));
  b.h = __float22bfloat162_rn(make_float2(f.z, f.w));
  return make_uint2(a.u, b.u);
}

DEV short8 mk8(uint2 lo, uint2 hi) {
  union { short8 s; uint4 u; } t;
  t.u = make_uint4(lo.x, lo.y, hi.x, hi.y);
  return t.s;
}

DEV uint32_t rotl32(uint32_t x, int r) { return (x << r) | (x >> (32 - r)); }

// JAX Threefry-2x32 with key = (0, 42)  (jax.random.key(42))
DEV void threefry_0_42(uint32_t x0, uint32_t x1, uint32_t& o0, uint32_t& o1) {
  const uint32_t ks0 = 0u, ks1 = 42u, ks2 = 0x1BD11BDAu ^ 42u;
  x0 += ks0; x1 += ks1;
#define TFR(r) { x0 += x1; x1 = rotl32(x1, (r)); x1 ^= x0; }
  TFR(13) TFR(15) TFR(26) TFR(6)  x0 += ks1; x1 += ks2 + 1u;
  TFR(17) TFR(29) TFR(16) TFR(24) x0 += ks2; x1 += ks0 + 2u;
  TFR(13) TFR(15) TFR(26) TFR(6)  x0 += ks0; x1 += ks1 + 3u;
  TFR(17) TFR(29) TFR(16) TFR(24) x0 += ks1; x1 += ks2 + 4u;
  TFR(13) TFR(15) TFR(26) TFR(6)  x0 += ks2; x1 += ks0 + 5u;
#undef TFR
  o0 = x0; o1 = x1;
}

DEV float wredmax(float v) {
#pragma unroll
  for (int off = 32; off > 0; off >>= 1) v = fmaxf(v, __shfl_xor(v, off));
  return v;
}
DEV float wredsum(float v) {
#pragma unroll
  for (int off = 32; off > 0; off >>= 1) v += __shfl_xor(v, off);
  return v;
}

// ---------------------------------------------------------------- prep: transposes + wq GEMM
// blocks 0..127: W_out tile transpose -> WoutT[512][1024] bf16
// blocks 128..135: W_ctx transpose -> WctxT[64][512] bf16
// blocks 136..151: wq2 = TWO_LOG2E*(input @ W_q)  (MFMA, B read direct/strided)
__global__ __launch_bounds__(256) void prep_kernel(const float* __restrict__ Wctx,
                                                   const float* __restrict__ Wq,
                                                   const float* __restrict__ Wout,
                                                   const float* __restrict__ input,
                                                   unsigned short* __restrict__ WctxT,
                                                   unsigned short* __restrict__ WoutT,
                                                   float* __restrict__ wq2) {
  const int b = blockIdx.x;
  const int tid = threadIdx.x;
  __shared__ float tile[64][65];
  __shared__ unsigned short As[64][32];
  if (b < 136) {
    const float* src; unsigned short* dst; int R, C, br, bc;
    if (b < 128) { src = Wout; dst = WoutT; R = 1024; C = 512; br = (b & 15) * 64; bc = (b >> 4) * 64; }
    else         { src = Wctx; dst = WctxT; R = 512;  C = 64;  br = (b - 128) * 64; bc = 0; }
    const int lr = tid >> 4, lc4 = (tid & 15) * 4;
#pragma unroll
    for (int i = 0; i < 4; ++i) {
      float4 v = *(const float4*)(src + (long)(br + lr + i * 16) * C + bc + lc4);
      tile[lr + i * 16][lc4 + 0] = v.x;
      tile[lr + i * 16][lc4 + 1] = v.y;
      tile[lr + i * 16][lc4 + 2] = v.z;
      tile[lr + i * 16][lc4 + 3] = v.w;
    }
    __syncthreads();
#pragma unroll
    for (int i = 0; i < 4; ++i) {
      int crow = lr + i * 16;
      ushort4 o;
      o.x = f2bf(tile[lc4 + 0][crow]);
      o.y = f2bf(tile[lc4 + 1][crow]);
      o.z = f2bf(tile[lc4 + 2][crow]);
      o.w = f2bf(tile[lc4 + 3][crow]);
      *(ushort4*)(dst + (long)(bc + crow) * R + br + lc4) = o;
    }
    return;
  }
  // ---- wq GEMM: 64 rows of input x W_q[512][64] ----
  const int mbase = (b - 136) * 64;
  const int srow = tid >> 2, kc = tid & 3;
  const int scol = ((kc ^ (srow & 3)) * 8);
  const int wave = tid >> 6, lane = tid & 63;
  const int wm = (wave >> 1) * 32, wn = (wave & 1) * 32;
  const int q = lane >> 4, r = lane & 15;
  const int c0 = ((q ^ (r & 3)) * 8);
  const float* ap = input + (long)(mbase + srow) * 512 + kc * 8;
  f32x4 acc[2][2];
#pragma unroll
  for (int i = 0; i < 2; ++i)
#pragma unroll
    for (int j = 0; j < 2; ++j) acc[i][j] = (f32x4){0.f, 0.f, 0.f, 0.f};
  for (int k0 = 0; k0 < 512; k0 += 32) {
    float4 fa0 = *(const float4*)(ap + k0);
    float4 fa1 = *(const float4*)(ap + k0 + 4);
    uint2 p0 = pk4(fa0), p1 = pk4(fa1);
    *(uint4*)&As[srow][scol] = make_uint4(p0.x, p0.y, p1.x, p1.y);
    __syncthreads();
    short8 bfrag[2];
#pragma unroll
    for (int j2 = 0; j2 < 2; ++j2) {
      float bv[8];
#pragma unroll
      for (int j = 0; j < 8; ++j)
        bv[j] = Wq[(long)(k0 + q * 8 + j) * 64 + wn + j2 * 16 + r];
      bfrag[j2] = mk8(pk4(make_float4(bv[0], bv[1], bv[2], bv[3])),
                      pk4(make_float4(bv[4], bv[5], bv[6], bv[7])));
    }
    short8 a0 = *(const short8*)&As[wm + r][c0];
    short8 a1 = *(const short8*)&As[wm + 16 + r][c0];
    acc[0][0] = __builtin_amdgcn_mfma_f32_16x16x32_bf16(a0, bfrag[0], acc[0][0], 0, 0, 0);
    acc[0][1] = __builtin_amdgcn_mfma_f32_16x16x32_bf16(a0, bfrag[1], acc[0][1], 0, 0, 0);
    acc[1][0] = __builtin_amdgcn_mfma_f32_16x16x32_bf16(a1, bfrag[0], acc[1][0], 0, 0, 0);
    acc[1][1] = __builtin_amdgcn_mfma_f32_16x16x32_bf16(a1, bfrag[1], acc[1][1], 0, 0, 0);
    __syncthreads();
  }
#pragma unroll
  for (int i2 = 0; i2 < 2; ++i2)
#pragma unroll
    for (int j2 = 0; j2 < 2; ++j2) {
      int gcol = wn + j2 * 16 + r;
#pragma unroll
      for (int reg = 0; reg < 4; ++reg)
        wq2[(long)(mbase + wm + i2 * 16 + q * 4 + reg) * 64 + gcol] =
            acc[i2][j2][reg] * TWO_LOG2E;
    }
}

// ---------------------------------------------------------------- uh GEMM + fused scores
// 256 blocks: block bx owns n = bx>>4, s-tile (bx&15)*64: computes uh[64s][64d] via
// MFMA, parks it in LDS, then sc[n][t][s-tile] for ALL 64 t (tanh-dot-v from LDS).
__global__ __launch_bounds__(256) void gemm_uh_scores(const float* __restrict__ mb,
                                                      const unsigned short* __restrict__ WctxT,
                                                      const float* __restrict__ wq2,
                                                      const float* __restrict__ v,
                                                      float* __restrict__ sc) {
  __shared__ unsigned short As[64][32];
  __shared__ unsigned short Bs[64][32];
  __shared__ float uhs[64][65];     // [s][d], +1 pad: uniform-d reads are 2-way (free)
  __shared__ float wqs[4096];       // [t][d] for this n, prescaled
  __shared__ float vs[64];
  const int tid = threadIdx.x;
  const int m0 = blockIdx.x * 64;                 // global mb row = n*1024 + s0
  const int n = m0 >> 10, s0 = m0 & 1023;
  const int srow = tid >> 2, kc = tid & 3;
  const int scol = ((kc ^ (srow & 3)) * 8);
  const int wave = tid >> 6, lane = tid & 63;
  const int wm = (wave >> 1) * 32, wn = (wave & 1) * 32;
  const int q = lane >> 4, r = lane & 15;
  const int c0 = ((q ^ (r & 3)) * 8);
  const float* ap = mb + (long)(m0 + srow) * 512 + kc * 8;
  const unsigned short* bp = WctxT + (long)srow * 512 + kc * 8;

  // stage wq panel + v for this n (consumed after K-loop; barriers inside cover)
#pragma unroll
  for (int i = 0; i < 4; ++i)
    *(float4*)&wqs[i * 1024 + tid * 4] = *(const float4*)(wq2 + (long)n * 4096 + i * 1024 + tid * 4);
  if (tid < 64) vs[tid] = v[tid];

  f32x4 acc[2][2];
#pragma unroll
  for (int i = 0; i < 2; ++i)
#pragma unroll
    for (int j = 0; j < 2; ++j) acc[i][j] = (f32x4){0.f, 0.f, 0.f, 0.f};

  float4 fa0 = *(const float4*)(ap);
  float4 fa1 = *(const float4*)(ap + 4);
  uint4 fb = *(const uint4*)(bp);
  for (int k0 = 0; k0 < 512; k0 += 32) {
    uint2 p0 = pk4(fa0), p1 = pk4(fa1);
    *(uint4*)&As[srow][scol] = make_uint4(p0.x, p0.y, p1.x, p1.y);
    *(uint4*)&Bs[srow][scol] = fb;
    __syncthreads();
    if (k0 + 32 < 512) {
      fa0 = *(const float4*)(ap + k0 + 32);
      fa1 = *(const float4*)(ap + k0 + 36);
      fb = *(const uint4*)(bp + k0 + 32);
    }
    short8 a0 = *(const short8*)&As[wm + r][c0];
    short8 a1 = *(const short8*)&As[wm + 16 + r][c0];
    short8 b0 = *(const short8*)&Bs[wn + r][c0];
    short8 b1 = *(const short8*)&Bs[wn + 16 + r][c0];
    acc[0][0] = __builtin_amdgcn_mfma_f32_16x16x32_bf16(a0, b0, acc[0][0], 0, 0, 0);
    acc[0][1] = __builtin_amdgcn_mfma_f32_16x16x32_bf16(a0, b1, acc[0][1], 0, 0, 0);
    acc[1][0] = __builtin_amdgcn_mfma_f32_16x16x32_bf16(a1, b0, acc[1][0], 0, 0, 0);
    acc[1][1] = __builtin_amdgcn_mfma_f32_16x16x32_bf16(a1, b1, acc[1][1], 0, 0, 0);
    __syncthreads();
  }
  // park uh tile (prescaled) in LDS: uhs[s][d]
#pragma unroll
  for (int i2 = 0; i2 < 2; ++i2)
#pragma unroll
    for (int j2 = 0; j2 < 2; ++j2)
#pragma unroll
      for (int reg = 0; reg < 4; ++reg)
        uhs[wm + i2 * 16 + q * 4 + reg][wn + j2 * 16 + r] = acc[i2][j2][reg] * TWO_LOG2E;
  __syncthreads();

  // fused scores: thread owns s = tid&63; its wave owns 16 t's.
  const int s = tid & 63;
  const int tbase = (tid >> 6) * 16;
  float sumv = 0.f;
#pragma unroll
  for (int c = 0; c < 64; c += 4) {
    float4 vv = *(const float4*)&vs[c];
    sumv += vv.x + vv.y + vv.z + vv.w;
  }
  float* scp = sc + (long)(n * 64 + tbase) * 1024 + s0 + s;
#pragma unroll
  for (int tg = 0; tg < 16; tg += 4) {
    const float* w0 = &wqs[(tbase + tg + 0) * 64];
    const float* w1 = &wqs[(tbase + tg + 1) * 64];
    const float* w2 = &wqs[(tbase + tg + 2) * 64];
    const float* w3 = &wqs[(tbase + tg + 3) * 64];
    float a0 = 0.f, a1 = 0.f, a2 = 0.f, a3 = 0.f;
    for (int c = 0; c < 64; ++c) {
      float u = uhs[s][c];           // lane-spread, 2-way banked (free)
      float vvc = vs[c];             // broadcast
      a0 = fmaf(vvc, __builtin_amdgcn_rcpf(1.f + __builtin_amdgcn_exp2f(u + w0[c])), a0);
      a1 = fmaf(vvc, __builtin_amdgcn_rcpf(1.f + __builtin_amdgcn_exp2f(u + w1[c])), a1);
      a2 = fmaf(vvc, __builtin_amdgcn_rcpf(1.f + __builtin_amdgcn_exp2f(u + w2[c])), a2);
      a3 = fmaf(vvc, __builtin_amdgcn_rcpf(1.f + __builtin_amdgcn_exp2f(u + w3[c])), a3);
    }
    scp[(long)(tg + 0) * 1024] = fmaf(-2.f, a0, sumv);
    scp[(long)(tg + 1) * 1024] = fmaf(-2.f, a1, sumv);
    scp[(long)(tg + 2) * 1024] = fmaf(-2.f, a2, sumv);
    scp[(long)(tg + 3) * 1024] = fmaf(-2.f, a3, sumv);
  }
}

// ---------------------------------------------------------------- softmax + gumbel
// 1024 blocks, one per nt. Thread owns 4 consecutive s. Reads sc, writes alpha+yal.
__global__ __launch_bounds__(256) void softmax_gumbel(const float* __restrict__ sc,
                                                      float* __restrict__ alpha_g,
                                                      float* __restrict__ y_g) {
  const int tid = threadIdx.x;
  const int nt = blockIdx.x;
  __shared__ float red[4];
  float4 l4 = *(const float4*)(sc + (long)nt * 1024 + tid * 4);
  float lsc[4] = {l4.x, l4.y, l4.z, l4.w};

  const int wv = tid >> 6, ln = tid & 63;
  float m = fmaxf(fmaxf(lsc[0], lsc[1]), fmaxf(lsc[2], lsc[3]));
  m = wredmax(m);
  if (ln == 0) red[wv] = m;
  __syncthreads();
  m = fmaxf(fmaxf(red[0], red[1]), fmaxf(red[2], red[3]));
  __syncthreads();
  float ss = 0.f;
#pragma unroll
  for (int i = 0; i < 4; ++i) ss += __expf(lsc[i] - m);
  ss = wredsum(ss);
  if (ln == 0) red[wv] = ss;
  __syncthreads();
  ss = red[0] + red[1] + red[2] + red[3];
  const float logl = __logf(ss);
  __syncthreads();

  const uint32_t jbase = (uint32_t)nt * 1024u + (uint32_t)tid * 4u;
  float ys[4];
  float4 av;
#pragma unroll
  for (int i = 0; i < 4; ++i) {
    float la = lsc[i] - m - logl;
    ((float*)&av)[i] = __expf(la);
    uint32_t o0, o1;
    threefry_0_42(0u, jbase + i, o0, o1);
    uint32_t bits = o0 ^ o1;
    float u = __uint_as_float((bits >> 9) | 0x3f800000u) - 1.0f;
    float g = -__logf(-__logf(u + 1e-20f) + 1e-20f);
    ys[i] = (la + g) * 2.0f;                           // /TEMPERATURE (0.5)
  }
  *(float4*)(alpha_g + (long)nt * 1024 + tid * 4) = av;

  float m2 = fmaxf(fmaxf(ys[0], ys[1]), fmaxf(ys[2], ys[3]));
  m2 = wredmax(m2);
  if (ln == 0) red[wv] = m2;
  __syncthreads();
  m2 = fmaxf(fmaxf(red[0], red[1]), fmaxf(red[2], red[3]));
  __syncthreads();
  float s2 = 0.f;
  float4 ye;
#pragma unroll
  for (int i = 0; i < 4; ++i) { ((float*)&ye)[i] = __expf(ys[i] - m2); s2 += ((float*)&ye)[i]; }
  s2 = wredsum(s2);
  if (ln == 0) red[wv] = s2;
  __syncthreads();
  s2 = red[0] + red[1] + red[2] + red[3];
  const float rinv = __fdividef(1.f, s2);
  ye.x *= rinv; ye.y *= rinv; ye.z *= rinv; ye.w *= rinv;
  *(float4*)(y_g + (long)nt * 1024 + tid * 4) = ye;
}

// ---------------------------------------------------------------- MFMA ctx GEMM, global-B
__global__ __launch_bounds__(256) void gemm_ctx_mfma(const float* __restrict__ alpha,
                                                     const float* __restrict__ yal,
                                                     const float* __restrict__ mb,
                                                     float* __restrict__ ctx) {
  __shared__ unsigned short As[64][32];
  const int tid = threadIdx.x;
  const int vt = blockIdx.x >> 4, n = blockIdx.x & 15;
  const int dbase = blockIdx.y * 32;
  const int srow = tid >> 2, kc = tid & 3;
  const int scol = ((kc ^ (srow & 3)) * 8);
  const int wave = tid >> 6, lane = tid & 63;
  const int wm = (wave >> 1) * 32, wn = (wave & 1) * 16;
  const int q = lane >> 4, r = lane & 15;
  const int c0 = ((q ^ (r & 3)) * 8);
  const float* Abase = (vt == 0 ? alpha : yal) + (long)n * 65536;
  const float* ap = Abase + (long)srow * 1024 + kc * 8;
  const float* bcol = mb + (long)n * 524288 + dbase + wn + r;  // + s*512
  f32x4 acc[2];
  acc[0] = (f32x4){0.f, 0.f, 0.f, 0.f};
  acc[1] = (f32x4){0.f, 0.f, 0.f, 0.f};

  float4 fa0 = *(const float4*)(ap);
  float4 fa1 = *(const float4*)(ap + 4);
  float bv[8];
#pragma unroll
  for (int j = 0; j < 8; ++j) bv[j] = bcol[(long)(q * 8 + j) * 512];

  for (int k0 = 0; k0 < 1024; k0 += 32) {
    uint2 p0 = pk4(fa0), p1 = pk4(fa1);
    *(uint4*)&As[srow][scol] = make_uint4(p0.x, p0.y, p1.x, p1.y);
    __syncthreads();
    float4 blo = make_float4(bv[0], bv[1], bv[2], bv[3]);
    float4 bhi = make_float4(bv[4], bv[5], bv[6], bv[7]);
    short8 b0 = mk8(pk4(blo), pk4(bhi));
    if (k0 + 32 < 1024) {
      fa0 = *(const float4*)(ap + k0 + 32);
      fa1 = *(const float4*)(ap + k0 + 36);
#pragma unroll
      for (int j = 0; j < 8; ++j) bv[j] = bcol[(long)(k0 + 32 + q * 8 + j) * 512];
    }
    short8 a0 = *(const short8*)&As[wm + r][c0];
    short8 a1 = *(const short8*)&As[wm + 16 + r][c0];
    acc[0] = __builtin_amdgcn_mfma_f32_16x16x32_bf16(a0, b0, acc[0], 0, 0, 0);
    acc[1] = __builtin_amdgcn_mfma_f32_16x16x32_bf16(a1, b0, acc[1], 0, 0, 0);
    __syncthreads();
  }
#pragma unroll
  for (int i2 = 0; i2 < 2; ++i2) {
    int gcol = dbase + wn + r;
#pragma unroll
    for (int reg = 0; reg < 4; ++reg) {
      long grow = (long)vt * 1024 + n * 64 + wm + i2 * 16 + q * 4 + reg;
      ctx[grow * 512 + gcol] = acc[i2][reg];
    }
  }
}

// ---------------------------------------------------------------- fused output GEMM (64x32)
__global__ __launch_bounds__(256) void gemm_out_mfma(const float* __restrict__ input,
                                                     const float* __restrict__ ctx,
                                                     const unsigned short* __restrict__ WoutT,
                                                     const float* __restrict__ bout,
                                                     float* __restrict__ out) {
  __shared__ unsigned short As[64][32];
  __shared__ unsigned short Bs[32][32];
  const int tid = threadIdx.x;
  const int mbase = blockIdx.x * 64, nbase = blockIdx.y * 32;
  const int srow = tid >> 2, kc = tid & 3;
  const int scol = ((kc ^ (srow & 3)) * 8);
  const int wave = tid >> 6, lane = tid & 63;
  const int wm = (wave >> 1) * 32, wn = (wave & 1) * 16;
  const int q = lane >> 4, r = lane & 15;
  const int c0 = ((q ^ (r & 3)) * 8);
  const int vv = mbase >> 10, nt = (mbase + srow) & 1023;
  const float* ap_lo = input + (long)nt * 512 + kc * 8;
  const float* ap_hi = ctx + (long)(vv * 1024 + nt) * 512 + kc * 8 - 512;
  const int brow = (tid & 127) >> 2;                  // 0..31 (tid<128 stages B)
  const unsigned short* bp = WoutT + (long)(nbase + brow) * 1024 + kc * 8;
  f32x4 acc[2];
  acc[0] = (f32x4){0.f, 0.f, 0.f, 0.f};
  acc[1] = (f32x4){0.f, 0.f, 0.f, 0.f};

  float4 fa0 = *(const float4*)(ap_lo);
  float4 fa1 = *(const float4*)(ap_lo + 4);
  uint4 fb;
  if (tid < 128) fb = *(const uint4*)(bp);
  for (int k0 = 0; k0 < 1024; k0 += 32) {
    uint2 p0 = pk4(fa0), p1 = pk4(fa1);
    *(uint4*)&As[srow][scol] = make_uint4(p0.x, p0.y, p1.x, p1.y);
    if (tid < 128) *(uint4*)&Bs[brow][(kc ^ (brow & 3)) * 8] = fb;
    __syncthreads();
    int kn = k0 + 32;
    if (kn < 1024) {
      const float* apn = (kn < 512) ? ap_lo : ap_hi;
      fa0 = *(const float4*)(apn + kn);
      fa1 = *(const float4*)(apn + kn + 4);
      if (tid < 128) fb = *(const uint4*)(bp + kn);
    }
    short8 a0 = *(const short8*)&As[wm + r][c0];
    short8 a1 = *(const short8*)&As[wm + 16 + r][c0];
    short8 b0 = *(const short8*)&Bs[wn + r][c0];
    acc[0] = __builtin_amdgcn_mfma_f32_16x16x32_bf16(a0, b0, acc[0], 0, 0, 0);
    acc[1] = __builtin_amdgcn_mfma_f32_16x16x32_bf16(a1, b0, acc[1], 0, 0, 0);
    __syncthreads();
  }
#pragma unroll
  for (int i2 = 0; i2 < 2; ++i2) {
    int gcol = nbase + wn + r;
    float bb = bout[gcol];
#pragma unroll
    for (int reg = 0; reg < 4; ++reg) {
      int grow = mbase + wm + i2 * 16 + q * 4 + reg;
      float z = acc[i2][reg] + bb;
      float rc = __builtin_amdgcn_rcpf(1.f + __builtin_amdgcn_exp2f(z * TWO_LOG2E));
      out[(long)grow * 512 + gcol] = fmaf(-2.f, rc, 1.f);
    }
  }
}

// ---------------------------------------------------------------- launch
// ws layout (float units):
//   sc    [0       , 1048576)   fp32 [1024][1024] scores (dead after softmax -> reused as ctx)
//   wq2   [1048576 , 1114112)   fp32 [1024][64], prescaled 2*log2e
//   yal   [1114112 , 2162688)   fp32 [1024][1024]
//   WctxT [2162688 , 2179072)   bf16 [64][512]
//   WoutT [2179072 , 2441216)   bf16 [512][1024]
// alpha staged in d_out, consumed by gemm_ctx before gemm_out overwrites it.
extern "C" void kernel_launch(void* const* d_in, const int* in_sizes, int n_in,
                              void* d_out, int out_size, void* d_ws, size_t ws_size,
                              hipStream_t stream) {
  const float* input = (const float*)d_in[0];   // [16,64,512]
  const float* mb    = (const float*)d_in[1];   // [16,1024,512]
  const float* W_q   = (const float*)d_in[2];   // [512,64]
  const float* W_ctx = (const float*)d_in[3];   // [512,64]
  const float* v     = (const float*)d_in[4];   // [64]
  const float* W_out = (const float*)d_in[5];   // [1024,512]
  const float* b_out = (const float*)d_in[6];   // [512]
  float* out = (float*)d_out;                   // [2,16,64,512]
  float* ws = (float*)d_ws;

  float* sc    = ws;
  float* wq2   = ws + 1048576;
  float* yal   = ws + 1114112;
  unsigned short* WctxT = (unsigned short*)(ws + 2162688);
  unsigned short* WoutT = (unsigned short*)(ws + 2179072);
  float* alpha = out;                 // staged in d_out
  float* ctx   = sc;                  // fp32 [2048][512], aliases dead sc

  prep_kernel<<<152, 256, 0, stream>>>(W_ctx, W_q, W_out, input, WctxT, WoutT, wq2);
  gemm_uh_scores<<<256, 256, 0, stream>>>(mb, WctxT, wq2, v, sc);
  softmax_gumbel<<<1024, 256, 0, stream>>>(sc, alpha, yal);
  gemm_ctx_mfma<<<dim3(32, 16), 256, 0, stream>>>(alpha, yal, mb, ctx);
  gemm_out_mfma<<<dim3(32, 16), 256, 0, stream>>>(input, ctx, WoutT, b_out, out);
}

// Round 10
// 165.537 us; speedup vs baseline: 1.0532x; 1.0532x over previous
//
#include <hip/hip_runtime.h>
#include <hip/hip_bf16.h>
#include <stdint.h>

#define DEV __device__ __forceinline__

typedef __attribute__((ext_vector_type(8))) short short8;   // 8 bf16 (4 VGPRs)
typedef __attribute__((ext_vector_type(4))) float f32x4;    // MFMA acc

#define TWO_LOG2E 2.8853900817779268f   // 2*log2(e): exp(2x) == exp2(x*TWO_LOG2E)

// ---------------------------------------------------------------- helpers
DEV unsigned short f2bf(float f) {           // fp32 -> bf16, RNE
  uint32_t u = __float_as_uint(f);
  u += 0x7FFFu + ((u >> 16) & 1u);
  return (unsigned short)(u >> 16);
}

DEV uint2 pk4(float4 f) {                    // 4 fp32 -> 4 bf16 (packed cvt)
  union { __hip_bfloat162 h; unsigned u; } a, b;
  a.h = __float22bfloat162_rn(make_float2(f.x, f.y));
  b.h = __float22bfloat162_rn(make_float2(f.z, f.w));
  return make_uint2(a.u, b.u);
}

DEV short8 mk8(uint2 lo, uint2 hi) {
  union { short8 s; uint4 u; } t;
  t.u = make_uint4(lo.x, lo.y, hi.x, hi.y);
  return t.s;
}

DEV uint32_t rotl32(uint32_t x, int r) { return (x << r) | (x >> (32 - r)); }

// JAX Threefry-2x32 with key = (0, 42)  (jax.random.key(42))
DEV void threefry_0_42(uint32_t x0, uint32_t x1, uint32_t& o0, uint32_t& o1) {
  const uint32_t ks0 = 0u, ks1 = 42u, ks2 = 0x1BD11BDAu ^ 42u;
  x0 += ks0; x1 += ks1;
#define TFR(r) { x0 += x1; x1 = rotl32(x1, (r)); x1 ^= x0; }
  TFR(13) TFR(15) TFR(26) TFR(6)  x0 += ks1; x1 += ks2 + 1u;
  TFR(17) TFR(29) TFR(16) TFR(24) x0 += ks2; x1 += ks0 + 2u;
  TFR(13) TFR(15) TFR(26) TFR(6)  x0 += ks0; x1 += ks1 + 3u;
  TFR(17) TFR(29) TFR(16) TFR(24) x0 += ks1; x1 += ks2 + 4u;
  TFR(13) TFR(15) TFR(26) TFR(6)  x0 += ks2; x1 += ks0 + 5u;
#undef TFR
  o0 = x0; o1 = x1;
}

DEV float wredmax(float v) {
#pragma unroll
  for (int off = 32; off > 0; off >>= 1) v = fmaxf(v, __shfl_xor(v, off));
  return v;
}
DEV float wredsum(float v) {
#pragma unroll
  for (int off = 32; off > 0; off >>= 1) v += __shfl_xor(v, off);
  return v;
}

// ---------------------------------------------------------------- prep: transposes + wq GEMM
// blocks 0..127: W_out tile transpose -> WoutT[512][1024] bf16
// blocks 128..135: W_ctx transpose -> WctxT[64][512] bf16
// blocks 136..151: wq2 = TWO_LOG2E*(input @ W_q)  (MFMA, B read direct/strided)
__global__ __launch_bounds__(256) void prep_kernel(const float* __restrict__ Wctx,
                                                   const float* __restrict__ Wq,
                                                   const float* __restrict__ Wout,
                                                   const float* __restrict__ input,
                                                   unsigned short* __restrict__ WctxT,
                                                   unsigned short* __restrict__ WoutT,
                                                   float* __restrict__ wq2) {
  const int b = blockIdx.x;
  const int tid = threadIdx.x;
  __shared__ float tile[64][65];
  __shared__ unsigned short As[64][32];
  if (b < 136) {
    const float* src; unsigned short* dst; int R, C, br, bc;
    if (b < 128) { src = Wout; dst = WoutT; R = 1024; C = 512; br = (b & 15) * 64; bc = (b >> 4) * 64; }
    else         { src = Wctx; dst = WctxT; R = 512;  C = 64;  br = (b - 128) * 64; bc = 0; }
    const int lr = tid >> 4, lc4 = (tid & 15) * 4;
#pragma unroll
    for (int i = 0; i < 4; ++i) {
      float4 v = *(const float4*)(src + (long)(br + lr + i * 16) * C + bc + lc4);
      tile[lr + i * 16][lc4 + 0] = v.x;
      tile[lr + i * 16][lc4 + 1] = v.y;
      tile[lr + i * 16][lc4 + 2] = v.z;
      tile[lr + i * 16][lc4 + 3] = v.w;
    }
    __syncthreads();
#pragma unroll
    for (int i = 0; i < 4; ++i) {
      int crow = lr + i * 16;
      ushort4 o;
      o.x = f2bf(tile[lc4 + 0][crow]);
      o.y = f2bf(tile[lc4 + 1][crow]);
      o.z = f2bf(tile[lc4 + 2][crow]);
      o.w = f2bf(tile[lc4 + 3][crow]);
      *(ushort4*)(dst + (long)(bc + crow) * R + br + lc4) = o;
    }
    return;
  }
  // ---- wq GEMM: 64 rows of input x W_q[512][64] ----
  const int mbase = (b - 136) * 64;
  const int srow = tid >> 2, kc = tid & 3;
  const int scol = ((kc ^ (srow & 3)) * 8);
  const int wave = tid >> 6, lane = tid & 63;
  const int wm = (wave >> 1) * 32, wn = (wave & 1) * 32;
  const int q = lane >> 4, r = lane & 15;
  const int c0 = ((q ^ (r & 3)) * 8);
  const float* ap = input + (long)(mbase + srow) * 512 + kc * 8;
  f32x4 acc[2][2];
#pragma unroll
  for (int i = 0; i < 2; ++i)
#pragma unroll
    for (int j = 0; j < 2; ++j) acc[i][j] = (f32x4){0.f, 0.f, 0.f, 0.f};
  for (int k0 = 0; k0 < 512; k0 += 32) {
    float4 fa0 = *(const float4*)(ap + k0);
    float4 fa1 = *(const float4*)(ap + k0 + 4);
    uint2 p0 = pk4(fa0), p1 = pk4(fa1);
    *(uint4*)&As[srow][scol] = make_uint4(p0.x, p0.y, p1.x, p1.y);
    __syncthreads();
    short8 bfrag[2];
#pragma unroll
    for (int j2 = 0; j2 < 2; ++j2) {
      float bv[8];
#pragma unroll
      for (int j = 0; j < 8; ++j)
        bv[j] = Wq[(long)(k0 + q * 8 + j) * 64 + wn + j2 * 16 + r];
      bfrag[j2] = mk8(pk4(make_float4(bv[0], bv[1], bv[2], bv[3])),
                      pk4(make_float4(bv[4], bv[5], bv[6], bv[7])));
    }
    short8 a0 = *(const short8*)&As[wm + r][c0];
    short8 a1 = *(const short8*)&As[wm + 16 + r][c0];
    acc[0][0] = __builtin_amdgcn_mfma_f32_16x16x32_bf16(a0, bfrag[0], acc[0][0], 0, 0, 0);
    acc[0][1] = __builtin_amdgcn_mfma_f32_16x16x32_bf16(a0, bfrag[1], acc[0][1], 0, 0, 0);
    acc[1][0] = __builtin_amdgcn_mfma_f32_16x16x32_bf16(a1, bfrag[0], acc[1][0], 0, 0, 0);
    acc[1][1] = __builtin_amdgcn_mfma_f32_16x16x32_bf16(a1, bfrag[1], acc[1][1], 0, 0, 0);
    __syncthreads();
  }
#pragma unroll
  for (int i2 = 0; i2 < 2; ++i2)
#pragma unroll
    for (int j2 = 0; j2 < 2; ++j2) {
      int gcol = wn + j2 * 16 + r;
#pragma unroll
      for (int reg = 0; reg < 4; ++reg)
        wq2[(long)(mbase + wm + i2 * 16 + q * 4 + reg) * 64 + gcol] =
            acc[i2][j2][reg] * TWO_LOG2E;
    }
}

// ---------------------------------------------------------------- uh GEMM (transposed out)
// 256 blocks: uhT[n][d][s] = TWO_LOG2E*(mb @ WctxT^T), K=512.
__global__ __launch_bounds__(256) void gemm_uh(const float* __restrict__ mb,
                                               const unsigned short* __restrict__ WctxT,
                                               float* __restrict__ uhT) {
  __shared__ unsigned short As[64][32];
  __shared__ unsigned short Bs[64][32];
  const int tid = threadIdx.x;
  const int mbase = blockIdx.x * 64;
  const int srow = tid >> 2, kc = tid & 3;
  const int scol = ((kc ^ (srow & 3)) * 8);
  const int wave = tid >> 6, lane = tid & 63;
  const int wm = (wave >> 1) * 32, wn = (wave & 1) * 32;
  const int q = lane >> 4, r = lane & 15;
  const int c0 = ((q ^ (r & 3)) * 8);
  const float* ap = mb + (long)(mbase + srow) * 512 + kc * 8;
  const unsigned short* bp = WctxT + (long)srow * 512 + kc * 8;
  f32x4 acc[2][2];
#pragma unroll
  for (int i = 0; i < 2; ++i)
#pragma unroll
    for (int j = 0; j < 2; ++j) acc[i][j] = (f32x4){0.f, 0.f, 0.f, 0.f};

  float4 fa0 = *(const float4*)(ap);
  float4 fa1 = *(const float4*)(ap + 4);
  uint4 fb = *(const uint4*)(bp);
  for (int k0 = 0; k0 < 512; k0 += 32) {
    uint2 p0 = pk4(fa0), p1 = pk4(fa1);
    *(uint4*)&As[srow][scol] = make_uint4(p0.x, p0.y, p1.x, p1.y);
    *(uint4*)&Bs[srow][scol] = fb;
    __syncthreads();
    if (k0 + 32 < 512) {
      fa0 = *(const float4*)(ap + k0 + 32);
      fa1 = *(const float4*)(ap + k0 + 36);
      fb = *(const uint4*)(bp + k0 + 32);
    }
    short8 a0 = *(const short8*)&As[wm + r][c0];
    short8 a1 = *(const short8*)&As[wm + 16 + r][c0];
    short8 b0 = *(const short8*)&Bs[wn + r][c0];
    short8 b1 = *(const short8*)&Bs[wn + 16 + r][c0];
    acc[0][0] = __builtin_amdgcn_mfma_f32_16x16x32_bf16(a0, b0, acc[0][0], 0, 0, 0);
    acc[0][1] = __builtin_amdgcn_mfma_f32_16x16x32_bf16(a0, b1, acc[0][1], 0, 0, 0);
    acc[1][0] = __builtin_amdgcn_mfma_f32_16x16x32_bf16(a1, b0, acc[1][0], 0, 0, 0);
    acc[1][1] = __builtin_amdgcn_mfma_f32_16x16x32_bf16(a1, b1, acc[1][1], 0, 0, 0);
    __syncthreads();
  }
#pragma unroll
  for (int i2 = 0; i2 < 2; ++i2)
#pragma unroll
    for (int j2 = 0; j2 < 2; ++j2) {
      int gcol = wn + j2 * 16 + r;                      // d
      int m = mbase + wm + i2 * 16 + q * 4;             // n*1024 + s (4 consecutive via reg)
      int n = m >> 10, s0 = m & 1023;
      float4 o;
      o.x = acc[i2][j2][0] * TWO_LOG2E;
      o.y = acc[i2][j2][1] * TWO_LOG2E;
      o.z = acc[i2][j2][2] * TWO_LOG2E;
      o.w = acc[i2][j2][3] * TWO_LOG2E;
      *(float4*)(uhT + (long)n * 65536 + (long)gcol * 1024 + s0) = o;
    }
}

// ---------------------------------------------------------------- tiled scores
// grid (16 s-tiles, 4 t-groups, 16 n) = 1024 blocks (4/CU). Block: stage uh tile
// [64d][64s] + wq rows [16t][64d] in LDS; thread owns s=tid&63 and 4 t's (wave-local);
// sc[n][t][s] = sumv - 2*sum_d v[d]*rcp(1+exp2(uh+wq)). 16x t-reuse of uh.
__global__ __launch_bounds__(256) void scores_tile(const float* __restrict__ uhT,
                                                   const float* __restrict__ wq2,
                                                   const float* __restrict__ v,
                                                   float* __restrict__ sc) {
  __shared__ float uhs[64][68];     // [d][s], pad 68 to spread cross-d banks
  __shared__ float wqs[16][64];
  __shared__ float vs[64];
  const int tid = threadIdx.x;
  const int s0 = blockIdx.x * 64, tb = blockIdx.y * 16, n = blockIdx.z;

  // stage wq rows (1024 contiguous floats) + v
  *(float4*)(&wqs[0][0] + tid * 4) =
      *(const float4*)(wq2 + ((long)n * 64 + tb) * 64 + tid * 4);
  if (tid < 64) vs[tid] = v[tid];
  // stage uh tile: 4 rows/wave per pass, 16 lanes x float4 = 256B contiguous per row
  {
    const int dr = tid >> 4, c4 = (tid & 15) * 4;
#pragma unroll
    for (int dk = 0; dk < 4; ++dk) {
      int d = dk * 16 + dr;
      *(float4*)&uhs[d][c4] = *(const float4*)(uhT + (long)n * 65536 + (long)d * 1024 + s0 + c4);
    }
  }
  __syncthreads();

  float sumv = 0.f;
#pragma unroll
  for (int c = 0; c < 64; c += 4) {
    float4 vv = *(const float4*)&vs[c];
    sumv += vv.x + vv.y + vv.z + vv.w;
  }

  const int s = tid & 63, wv = tid >> 6;
  const float* w0 = &wqs[wv * 4 + 0][0];
  const float* w1 = &wqs[wv * 4 + 1][0];
  const float* w2 = &wqs[wv * 4 + 2][0];
  const float* w3 = &wqs[wv * 4 + 3][0];
  float a0 = 0.f, a1 = 0.f, a2 = 0.f, a3 = 0.f;
#pragma unroll 16
  for (int d = 0; d < 64; ++d) {
    float u = uhs[d][s];             // lane-spread stride-1: free 2-way
    float vd = vs[d];                // broadcast
    a0 = fmaf(vd, __builtin_amdgcn_rcpf(1.f + __builtin_amdgcn_exp2f(u + w0[d])), a0);
    a1 = fmaf(vd, __builtin_amdgcn_rcpf(1.f + __builtin_amdgcn_exp2f(u + w1[d])), a1);
    a2 = fmaf(vd, __builtin_amdgcn_rcpf(1.f + __builtin_amdgcn_exp2f(u + w2[d])), a2);
    a3 = fmaf(vd, __builtin_amdgcn_rcpf(1.f + __builtin_amdgcn_exp2f(u + w3[d])), a3);
  }
  float* scp = sc + ((long)n * 64 + tb + wv * 4) * 1024 + s0 + s;
  scp[0]    = fmaf(-2.f, a0, sumv);
  scp[1024] = fmaf(-2.f, a1, sumv);
  scp[2048] = fmaf(-2.f, a2, sumv);
  scp[3072] = fmaf(-2.f, a3, sumv);
}

// ---------------------------------------------------------------- softmax + gumbel
__global__ __launch_bounds__(256) void softmax_gumbel(const float* __restrict__ sc,
                                                      float* __restrict__ alpha_g,
                                                      float* __restrict__ y_g) {
  const int tid = threadIdx.x;
  const int nt = blockIdx.x;
  __shared__ float red[4];
  float4 l4 = *(const float4*)(sc + (long)nt * 1024 + tid * 4);
  float lsc[4] = {l4.x, l4.y, l4.z, l4.w};

  const int wv = tid >> 6, ln = tid & 63;
  float m = fmaxf(fmaxf(lsc[0], lsc[1]), fmaxf(lsc[2], lsc[3]));
  m = wredmax(m);
  if (ln == 0) red[wv] = m;
  __syncthreads();
  m = fmaxf(fmaxf(red[0], red[1]), fmaxf(red[2], red[3]));
  __syncthreads();
  float ss = 0.f;
#pragma unroll
  for (int i = 0; i < 4; ++i) ss += __expf(lsc[i] - m);
  ss = wredsum(ss);
  if (ln == 0) red[wv] = ss;
  __syncthreads();
  ss = red[0] + red[1] + red[2] + red[3];
  const float logl = __logf(ss);
  __syncthreads();

  const uint32_t jbase = (uint32_t)nt * 1024u + (uint32_t)tid * 4u;
  float ys[4];
  float4 av;
#pragma unroll
  for (int i = 0; i < 4; ++i) {
    float la = lsc[i] - m - logl;
    ((float*)&av)[i] = __expf(la);
    uint32_t o0, o1;
    threefry_0_42(0u, jbase + i, o0, o1);
    uint32_t bits = o0 ^ o1;
    float u = __uint_as_float((bits >> 9) | 0x3f800000u) - 1.0f;
    float g = -__logf(-__logf(u + 1e-20f) + 1e-20f);
    ys[i] = (la + g) * 2.0f;                           // /TEMPERATURE (0.5)
  }
  *(float4*)(alpha_g + (long)nt * 1024 + tid * 4) = av;

  float m2 = fmaxf(fmaxf(ys[0], ys[1]), fmaxf(ys[2], ys[3]));
  m2 = wredmax(m2);
  if (ln == 0) red[wv] = m2;
  __syncthreads();
  m2 = fmaxf(fmaxf(red[0], red[1]), fmaxf(red[2], red[3]));
  __syncthreads();
  float s2 = 0.f;
  float4 ye;
#pragma unroll
  for (int i = 0; i < 4; ++i) { ((float*)&ye)[i] = __expf(ys[i] - m2); s2 += ((float*)&ye)[i]; }
  s2 = wredsum(s2);
  if (ln == 0) red[wv] = s2;
  __syncthreads();
  s2 = red[0] + red[1] + red[2] + red[3];
  const float rinv = __fdividef(1.f, s2);
  ye.x *= rinv; ye.y *= rinv; ye.z *= rinv; ye.w *= rinv;
  *(float4*)(y_g + (long)nt * 1024 + tid * 4) = ye;
}

// ---------------------------------------------------------------- MFMA ctx GEMM, global-B
__global__ __launch_bounds__(256) void gemm_ctx_mfma(const float* __restrict__ alpha,
                                                     const float* __restrict__ yal,
                                                     const float* __restrict__ mb,
                                                     float* __restrict__ ctx) {
  __shared__ unsigned short As[64][32];
  const int tid = threadIdx.x;
  const int vt = blockIdx.x >> 4, n = blockIdx.x & 15;
  const int dbase = blockIdx.y * 32;
  const int srow = tid >> 2, kc = tid & 3;
  const int scol = ((kc ^ (srow & 3)) * 8);
  const int wave = tid >> 6, lane = tid & 63;
  const int wm = (wave >> 1) * 32, wn = (wave & 1) * 16;
  const int q = lane >> 4, r = lane & 15;
  const int c0 = ((q ^ (r & 3)) * 8);
  const float* Abase = (vt == 0 ? alpha : yal) + (long)n * 65536;
  const float* ap = Abase + (long)srow * 1024 + kc * 8;
  const float* bcol = mb + (long)n * 524288 + dbase + wn + r;  // + s*512
  f32x4 acc[2];
  acc[0] = (f32x4){0.f, 0.f, 0.f, 0.f};
  acc[1] = (f32x4){0.f, 0.f, 0.f, 0.f};

  float4 fa0 = *(const float4*)(ap);
  float4 fa1 = *(const float4*)(ap + 4);
  float bv[8];
#pragma unroll
  for (int j = 0; j < 8; ++j) bv[j] = bcol[(long)(q * 8 + j) * 512];

  for (int k0 = 0; k0 < 1024; k0 += 32) {
    uint2 p0 = pk4(fa0), p1 = pk4(fa1);
    *(uint4*)&As[srow][scol] = make_uint4(p0.x, p0.y, p1.x, p1.y);
    __syncthreads();
    float4 blo = make_float4(bv[0], bv[1], bv[2], bv[3]);
    float4 bhi = make_float4(bv[4], bv[5], bv[6], bv[7]);
    short8 b0 = mk8(pk4(blo), pk4(bhi));
    if (k0 + 32 < 1024) {
      fa0 = *(const float4*)(ap + k0 + 32);
      fa1 = *(const float4*)(ap + k0 + 36);
#pragma unroll
      for (int j = 0; j < 8; ++j) bv[j] = bcol[(long)(k0 + 32 + q * 8 + j) * 512];
    }
    short8 a0 = *(const short8*)&As[wm + r][c0];
    short8 a1 = *(const short8*)&As[wm + 16 + r][c0];
    acc[0] = __builtin_amdgcn_mfma_f32_16x16x32_bf16(a0, b0, acc[0], 0, 0, 0);
    acc[1] = __builtin_amdgcn_mfma_f32_16x16x32_bf16(a1, b0, acc[1], 0, 0, 0);
    __syncthreads();
  }
#pragma unroll
  for (int i2 = 0; i2 < 2; ++i2) {
    int gcol = dbase + wn + r;
#pragma unroll
    for (int reg = 0; reg < 4; ++reg) {
      long grow = (long)vt * 1024 + n * 64 + wm + i2 * 16 + q * 4 + reg;
      ctx[grow * 512 + gcol] = acc[i2][reg];
    }
  }
}

// ---------------------------------------------------------------- fused output GEMM (64x32)
__global__ __launch_bounds__(256) void gemm_out_mfma(const float* __restrict__ input,
                                                     const float* __restrict__ ctx,
                                                     const unsigned short* __restrict__ WoutT,
                                                     const float* __restrict__ bout,
                                                     float* __restrict__ out) {
  __shared__ unsigned short As[64][32];
  __shared__ unsigned short Bs[32][32];
  const int tid = threadIdx.x;
  const int mbase = blockIdx.x * 64, nbase = blockIdx.y * 32;
  const int srow = tid >> 2, kc = tid & 3;
  const int scol = ((kc ^ (srow & 3)) * 8);
  const int wave = tid >> 6, lane = tid & 63;
  const int wm = (wave >> 1) * 32, wn = (wave & 1) * 16;
  const int q = lane >> 4, r = lane & 15;
  const int c0 = ((q ^ (r & 3)) * 8);
  const int vv = mbase >> 10, nt = (mbase + srow) & 1023;
  const float* ap_lo = input + (long)nt * 512 + kc * 8;
  const float* ap_hi = ctx + (long)(vv * 1024 + nt) * 512 + kc * 8 - 512;
  const int brow = (tid & 127) >> 2;                  // 0..31 (tid<128 stages B)
  const unsigned short* bp = WoutT + (long)(nbase + brow) * 1024 + kc * 8;
  f32x4 acc[2];
  acc[0] = (f32x4){0.f, 0.f, 0.f, 0.f};
  acc[1] = (f32x4){0.f, 0.f, 0.f, 0.f};

  float4 fa0 = *(const float4*)(ap_lo);
  float4 fa1 = *(const float4*)(ap_lo + 4);
  uint4 fb;
  if (tid < 128) fb = *(const uint4*)(bp);
  for (int k0 = 0; k0 < 1024; k0 += 32) {
    uint2 p0 = pk4(fa0), p1 = pk4(fa1);
    *(uint4*)&As[srow][scol] = make_uint4(p0.x, p0.y, p1.x, p1.y);
    if (tid < 128) *(uint4*)&Bs[brow][(kc ^ (brow & 3)) * 8] = fb;
    __syncthreads();
    int kn = k0 + 32;
    if (kn < 1024) {
      const float* apn = (kn < 512) ? ap_lo : ap_hi;
      fa0 = *(const float4*)(apn + kn);
      fa1 = *(const float4*)(apn + kn + 4);
      if (tid < 128) fb = *(const uint4*)(bp + kn);
    }
    short8 a0 = *(const short8*)&As[wm + r][c0];
    short8 a1 = *(const short8*)&As[wm + 16 + r][c0];
    short8 b0 = *(const short8*)&Bs[wn + r][c0];
    acc[0] = __builtin_amdgcn_mfma_f32_16x16x32_bf16(a0, b0, acc[0], 0, 0, 0);
    acc[1] = __builtin_amdgcn_mfma_f32_16x16x32_bf16(a1, b0, acc[1], 0, 0, 0);
    __syncthreads();
  }
#pragma unroll
  for (int i2 = 0; i2 < 2; ++i2) {
    int gcol = nbase + wn + r;
    float bb = bout[gcol];
#pragma unroll
    for (int reg = 0; reg < 4; ++reg) {
      int grow = mbase + wm + i2 * 16 + q * 4 + reg;
      float z = acc[i2][reg] + bb;
      float rc = __builtin_amdgcn_rcpf(1.f + __builtin_amdgcn_exp2f(z * TWO_LOG2E));
      out[(long)grow * 512 + gcol] = fmaf(-2.f, rc, 1.f);
    }
  }
}

// ---------------------------------------------------------------- launch
// ws layout (float units):
//   uhT   [0       , 1048576)   fp32 [16][64][1024], prescaled (dead after scores -> ctx)
//   wq2   [1048576 , 1114112)   fp32 [1024][64], prescaled
//   yal   [1114112 , 2162688)   fp32 [1024][1024]
//   sc    [2162688 , 3211264)   fp32 [1024][1024]
//   WctxT [3211264 , 3227648)   bf16 [64][512]
//   WoutT [3227648 , 3489792)   bf16 [512][1024]
// alpha staged in d_out, consumed by gemm_ctx before gemm_out overwrites it.
extern "C" void kernel_launch(void* const* d_in, const int* in_sizes, int n_in,
                              void* d_out, int out_size, void* d_ws, size_t ws_size,
                              hipStream_t stream) {
  const float* input = (const float*)d_in[0];   // [16,64,512]
  const float* mb    = (const float*)d_in[1];   // [16,1024,512]
  const float* W_q   = (const float*)d_in[2];   // [512,64]
  const float* W_ctx = (const float*)d_in[3];   // [512,64]
  const float* v     = (const float*)d_in[4];   // [64]
  const float* W_out = (const float*)d_in[5];   // [1024,512]
  const float* b_out = (const float*)d_in[6];   // [512]
  float* out = (float*)d_out;                   // [2,16,64,512]
  float* ws = (float*)d_ws;

  float* uhT   = ws;
  float* wq2   = ws + 1048576;
  float* yal   = ws + 1114112;
  float* sc    = ws + 2162688;
  unsigned short* WctxT = (unsigned short*)(ws + 3211264);
  unsigned short* WoutT = (unsigned short*)(ws + 3227648);
  float* alpha = out;                 // staged in d_out
  float* ctx   = uhT;                 // fp32 [2048][512], aliases dead uhT

  prep_kernel<<<152, 256, 0, stream>>>(W_ctx, W_q, W_out, input, WctxT, WoutT, wq2);
  gemm_uh<<<256, 256, 0, stream>>>(mb, WctxT, uhT);
  scores_tile<<<dim3(16, 4, 16), 256, 0, stream>>>(uhT, wq2, v, sc);
  softmax_gumbel<<<1024, 256, 0, stream>>>(sc, alpha, yal);
  gemm_ctx_mfma<<<dim3(32, 16), 256, 0, stream>>>(alpha, yal, mb, ctx);
  gemm_out_mfma<<<dim3(32, 16), 256, 0, stream>>>(input, ctx, WoutT, b_out, out);
}

// Round 11
// 155.502 us; speedup vs baseline: 1.1212x; 1.0645x over previous
//
#include <hip/hip_runtime.h>
#include <hip/hip_bf16.h>
#include <stdint.h>

#define DEV __device__ __forceinline__

typedef __attribute__((ext_vector_type(8))) short short8;   // 8 bf16 (4 VGPRs)
typedef __attribute__((ext_vector_type(4))) float f32x4;    // MFMA acc

#define TWO_LOG2E 2.8853900817779268f   // 2*log2(e): exp(2x) == exp2(x*TWO_LOG2E)

// ---------------------------------------------------------------- helpers
DEV unsigned short f2bf(float f) {           // fp32 -> bf16, RNE
  uint32_t u = __float_as_uint(f);
  u += 0x7FFFu + ((u >> 16) & 1u);
  return (unsigned short)(u >> 16);
}

DEV uint2 pk4(float4 f) {                    // 4 fp32 -> 4 bf16 (packed cvt)
  union { __hip_bfloat162 h; unsigned u; } a, b;
  a.h = __float22bfloat162_rn(make_float2(f.x, f.y));
  b.h = __float22bfloat162_rn(make_float2(f.z, f.w));
  return make_uint2(a.u, b.u);
}

DEV short8 mk8(uint2 lo, uint2 hi) {
  union { short8 s; uint4 u; } t;
  t.u = make_uint4(lo.x, lo.y, hi.x, hi.y);
  return t.s;
}

DEV uint32_t rotl32(uint32_t x, int r) { return (x << r) | (x >> (32 - r)); }

// JAX Threefry-2x32 with key = (0, 42)  (jax.random.key(42))
DEV void threefry_0_42(uint32_t x0, uint32_t x1, uint32_t& o0, uint32_t& o1) {
  const uint32_t ks0 = 0u, ks1 = 42u, ks2 = 0x1BD11BDAu ^ 42u;
  x0 += ks0; x1 += ks1;
#define TFR(r) { x0 += x1; x1 = rotl32(x1, (r)); x1 ^= x0; }
  TFR(13) TFR(15) TFR(26) TFR(6)  x0 += ks1; x1 += ks2 + 1u;
  TFR(17) TFR(29) TFR(16) TFR(24) x0 += ks2; x1 += ks0 + 2u;
  TFR(13) TFR(15) TFR(26) TFR(6)  x0 += ks0; x1 += ks1 + 3u;
  TFR(17) TFR(29) TFR(16) TFR(24) x0 += ks1; x1 += ks2 + 4u;
  TFR(13) TFR(15) TFR(26) TFR(6)  x0 += ks2; x1 += ks0 + 5u;
#undef TFR
  o0 = x0; o1 = x1;
}

DEV float wredmax(float v) {
#pragma unroll
  for (int off = 32; off > 0; off >>= 1) v = fmaxf(v, __shfl_xor(v, off));
  return v;
}
DEV float wredsum(float v) {
#pragma unroll
  for (int off = 32; off > 0; off >>= 1) v += __shfl_xor(v, off);
  return v;
}

// ---------------------------------------------------------------- prep
// blocks 0..127: W_out transpose -> WoutT[512][1024] bf16
// blocks 128..135: W_ctx transpose -> WctxT[64][512] bf16
// blocks 136..151: input -> inputB bf16 (straight cast)
// blocks 152..167: wq2 = TWO_LOG2E*(input @ W_q)  (MFMA, strided B)
__global__ __launch_bounds__(256) void prep_kernel(const float* __restrict__ Wctx,
                                                   const float* __restrict__ Wq,
                                                   const float* __restrict__ Wout,
                                                   const float* __restrict__ input,
                                                   unsigned short* __restrict__ WctxT,
                                                   unsigned short* __restrict__ WoutT,
                                                   unsigned short* __restrict__ inputB,
                                                   float* __restrict__ wq2) {
  const int b = blockIdx.x;
  const int tid = threadIdx.x;
  __shared__ float tile[64][65];
  __shared__ unsigned short As[64][32];
  if (b < 136) {
    const float* src; unsigned short* dst; int R, C, br, bc;
    if (b < 128) { src = Wout; dst = WoutT; R = 1024; C = 512; br = (b & 15) * 64; bc = (b >> 4) * 64; }
    else         { src = Wctx; dst = WctxT; R = 512;  C = 64;  br = (b - 128) * 64; bc = 0; }
    const int lr = tid >> 4, lc4 = (tid & 15) * 4;
#pragma unroll
    for (int i = 0; i < 4; ++i) {
      float4 v = *(const float4*)(src + (long)(br + lr + i * 16) * C + bc + lc4);
      tile[lr + i * 16][lc4 + 0] = v.x;
      tile[lr + i * 16][lc4 + 1] = v.y;
      tile[lr + i * 16][lc4 + 2] = v.z;
      tile[lr + i * 16][lc4 + 3] = v.w;
    }
    __syncthreads();
#pragma unroll
    for (int i = 0; i < 4; ++i) {
      int crow = lr + i * 16;
      ushort4 o;
      o.x = f2bf(tile[lc4 + 0][crow]);
      o.y = f2bf(tile[lc4 + 1][crow]);
      o.z = f2bf(tile[lc4 + 2][crow]);
      o.w = f2bf(tile[lc4 + 3][crow]);
      *(ushort4*)(dst + (long)(bc + crow) * R + br + lc4) = o;
    }
    return;
  }
  if (b < 152) {                               // inputB cast: 32768 elems/block
    const long base = (long)(b - 136) * 32768;
#pragma unroll
    for (int it = 0; it < 32; ++it) {
      long e = base + (it * 256 + tid) * 4;
      float4 f = *(const float4*)(input + e);
      *(uint2*)(inputB + e) = pk4(f);
    }
    return;
  }
  // ---- wq GEMM: 64 rows of input x W_q[512][64] ----
  const int mbase = (b - 152) * 64;
  const int srow = tid >> 2, kc = tid & 3;
  const int scol = ((kc ^ (srow & 3)) * 8);
  const int wave = tid >> 6, lane = tid & 63;
  const int wm = (wave >> 1) * 32, wn = (wave & 1) * 32;
  const int q = lane >> 4, r = lane & 15;
  const int c0 = ((q ^ (r & 3)) * 8);
  const float* ap = input + (long)(mbase + srow) * 512 + kc * 8;
  f32x4 acc[2][2];
#pragma unroll
  for (int i = 0; i < 2; ++i)
#pragma unroll
    for (int j = 0; j < 2; ++j) acc[i][j] = (f32x4){0.f, 0.f, 0.f, 0.f};
  for (int k0 = 0; k0 < 512; k0 += 32) {
    float4 fa0 = *(const float4*)(ap + k0);
    float4 fa1 = *(const float4*)(ap + k0 + 4);
    uint2 p0 = pk4(fa0), p1 = pk4(fa1);
    *(uint4*)&As[srow][scol] = make_uint4(p0.x, p0.y, p1.x, p1.y);
    __syncthreads();
    short8 bfrag[2];
#pragma unroll
    for (int j2 = 0; j2 < 2; ++j2) {
      float bv[8];
#pragma unroll
      for (int j = 0; j < 8; ++j)
        bv[j] = Wq[(long)(k0 + q * 8 + j) * 64 + wn + j2 * 16 + r];
      bfrag[j2] = mk8(pk4(make_float4(bv[0], bv[1], bv[2], bv[3])),
                      pk4(make_float4(bv[4], bv[5], bv[6], bv[7])));
    }
    short8 a0 = *(const short8*)&As[wm + r][c0];
    short8 a1 = *(const short8*)&As[wm + 16 + r][c0];
    acc[0][0] = __builtin_amdgcn_mfma_f32_16x16x32_bf16(a0, bfrag[0], acc[0][0], 0, 0, 0);
    acc[0][1] = __builtin_amdgcn_mfma_f32_16x16x32_bf16(a0, bfrag[1], acc[0][1], 0, 0, 0);
    acc[1][0] = __builtin_amdgcn_mfma_f32_16x16x32_bf16(a1, bfrag[0], acc[1][0], 0, 0, 0);
    acc[1][1] = __builtin_amdgcn_mfma_f32_16x16x32_bf16(a1, bfrag[1], acc[1][1], 0, 0, 0);
    __syncthreads();
  }
#pragma unroll
  for (int i2 = 0; i2 < 2; ++i2)
#pragma unroll
    for (int j2 = 0; j2 < 2; ++j2) {
      int gcol = wn + j2 * 16 + r;
#pragma unroll
      for (int reg = 0; reg < 4; ++reg)
        wq2[(long)(mbase + wm + i2 * 16 + q * 4 + reg) * 64 + gcol] =
            acc[i2][j2][reg] * TWO_LOG2E;
    }
}

// ---------------------------------------------------------------- uh GEMM (transposed out)
// 256 blocks: uhT[n][d][s] = TWO_LOG2E*(mb @ WctxT^T), K=512.
__global__ __launch_bounds__(256) void gemm_uh(const float* __restrict__ mb,
                                               const unsigned short* __restrict__ WctxT,
                                               float* __restrict__ uhT) {
  __shared__ unsigned short As[64][32];
  __shared__ unsigned short Bs[64][32];
  const int tid = threadIdx.x;
  const int mbase = blockIdx.x * 64;
  const int srow = tid >> 2, kc = tid & 3;
  const int scol = ((kc ^ (srow & 3)) * 8);
  const int wave = tid >> 6, lane = tid & 63;
  const int wm = (wave >> 1) * 32, wn = (wave & 1) * 32;
  const int q = lane >> 4, r = lane & 15;
  const int c0 = ((q ^ (r & 3)) * 8);
  const float* ap = mb + (long)(mbase + srow) * 512 + kc * 8;
  const unsigned short* bp = WctxT + (long)srow * 512 + kc * 8;
  f32x4 acc[2][2];
#pragma unroll
  for (int i = 0; i < 2; ++i)
#pragma unroll
    for (int j = 0; j < 2; ++j) acc[i][j] = (f32x4){0.f, 0.f, 0.f, 0.f};

  float4 fa0 = *(const float4*)(ap);
  float4 fa1 = *(const float4*)(ap + 4);
  uint4 fb = *(const uint4*)(bp);
  for (int k0 = 0; k0 < 512; k0 += 32) {
    uint2 p0 = pk4(fa0), p1 = pk4(fa1);
    *(uint4*)&As[srow][scol] = make_uint4(p0.x, p0.y, p1.x, p1.y);
    *(uint4*)&Bs[srow][scol] = fb;
    __syncthreads();
    if (k0 + 32 < 512) {
      fa0 = *(const float4*)(ap + k0 + 32);
      fa1 = *(const float4*)(ap + k0 + 36);
      fb = *(const uint4*)(bp + k0 + 32);
    }
    short8 a0 = *(const short8*)&As[wm + r][c0];
    short8 a1 = *(const short8*)&As[wm + 16 + r][c0];
    short8 b0 = *(const short8*)&Bs[wn + r][c0];
    short8 b1 = *(const short8*)&Bs[wn + 16 + r][c0];
    acc[0][0] = __builtin_amdgcn_mfma_f32_16x16x32_bf16(a0, b0, acc[0][0], 0, 0, 0);
    acc[0][1] = __builtin_amdgcn_mfma_f32_16x16x32_bf16(a0, b1, acc[0][1], 0, 0, 0);
    acc[1][0] = __builtin_amdgcn_mfma_f32_16x16x32_bf16(a1, b0, acc[1][0], 0, 0, 0);
    acc[1][1] = __builtin_amdgcn_mfma_f32_16x16x32_bf16(a1, b1, acc[1][1], 0, 0, 0);
    __syncthreads();
  }
#pragma unroll
  for (int i2 = 0; i2 < 2; ++i2)
#pragma unroll
    for (int j2 = 0; j2 < 2; ++j2) {
      int gcol = wn + j2 * 16 + r;                      // d
      int m = mbase + wm + i2 * 16 + q * 4;             // n*1024 + s (4 consecutive via reg)
      int n = m >> 10, s0 = m & 1023;
      float4 o;
      o.x = acc[i2][j2][0] * TWO_LOG2E;
      o.y = acc[i2][j2][1] * TWO_LOG2E;
      o.z = acc[i2][j2][2] * TWO_LOG2E;
      o.w = acc[i2][j2][3] * TWO_LOG2E;
      *(float4*)(uhT + (long)n * 65536 + (long)gcol * 1024 + s0) = o;
    }
}

// ---------------------------------------------------------------- tiled scores
// grid (16 s-tiles, 4 t-groups, 16 n) = 1024 blocks (4/CU).
__global__ __launch_bounds__(256) void scores_tile(const float* __restrict__ uhT,
                                                   const float* __restrict__ wq2,
                                                   const float* __restrict__ v,
                                                   float* __restrict__ sc) {
  __shared__ float uhs[64][68];
  __shared__ float wqs[16][64];
  __shared__ float vs[64];
  const int tid = threadIdx.x;
  const int s0 = blockIdx.x * 64, tb = blockIdx.y * 16, n = blockIdx.z;

  *(float4*)(&wqs[0][0] + tid * 4) =
      *(const float4*)(wq2 + ((long)n * 64 + tb) * 64 + tid * 4);
  if (tid < 64) vs[tid] = v[tid];
  {
    const int dr = tid >> 4, c4 = (tid & 15) * 4;
#pragma unroll
    for (int dk = 0; dk < 4; ++dk) {
      int d = dk * 16 + dr;
      *(float4*)&uhs[d][c4] = *(const float4*)(uhT + (long)n * 65536 + (long)d * 1024 + s0 + c4);
    }
  }
  __syncthreads();

  float sumv = 0.f;
#pragma unroll
  for (int c = 0; c < 64; c += 4) {
    float4 vv = *(const float4*)&vs[c];
    sumv += vv.x + vv.y + vv.z + vv.w;
  }

  const int s = tid & 63, wv = tid >> 6;
  const float* w0 = &wqs[wv * 4 + 0][0];
  const float* w1 = &wqs[wv * 4 + 1][0];
  const float* w2 = &wqs[wv * 4 + 2][0];
  const float* w3 = &wqs[wv * 4 + 3][0];
  float a0 = 0.f, a1 = 0.f, a2 = 0.f, a3 = 0.f;
#pragma unroll 16
  for (int d = 0; d < 64; ++d) {
    float u = uhs[d][s];
    float vd = vs[d];
    a0 = fmaf(vd, __builtin_amdgcn_rcpf(1.f + __builtin_amdgcn_exp2f(u + w0[d])), a0);
    a1 = fmaf(vd, __builtin_amdgcn_rcpf(1.f + __builtin_amdgcn_exp2f(u + w1[d])), a1);
    a2 = fmaf(vd, __builtin_amdgcn_rcpf(1.f + __builtin_amdgcn_exp2f(u + w2[d])), a2);
    a3 = fmaf(vd, __builtin_amdgcn_rcpf(1.f + __builtin_amdgcn_exp2f(u + w3[d])), a3);
  }
  float* scp = sc + ((long)n * 64 + tb + wv * 4) * 1024 + s0 + s;
  scp[0]    = fmaf(-2.f, a0, sumv);
  scp[1024] = fmaf(-2.f, a1, sumv);
  scp[2048] = fmaf(-2.f, a2, sumv);
  scp[3072] = fmaf(-2.f, a3, sumv);
}

// ---------------------------------------------------------------- softmax + gumbel -> bf16
__global__ __launch_bounds__(256) void softmax_gumbel(const float* __restrict__ sc,
                                                      unsigned short* __restrict__ alphaB,
                                                      unsigned short* __restrict__ yalB) {
  const int tid = threadIdx.x;
  const int nt = blockIdx.x;
  __shared__ float red[4];
  float4 l4 = *(const float4*)(sc + (long)nt * 1024 + tid * 4);
  float lsc[4] = {l4.x, l4.y, l4.z, l4.w};

  const int wv = tid >> 6, ln = tid & 63;
  float m = fmaxf(fmaxf(lsc[0], lsc[1]), fmaxf(lsc[2], lsc[3]));
  m = wredmax(m);
  if (ln == 0) red[wv] = m;
  __syncthreads();
  m = fmaxf(fmaxf(red[0], red[1]), fmaxf(red[2], red[3]));
  __syncthreads();
  float ss = 0.f;
#pragma unroll
  for (int i = 0; i < 4; ++i) ss += __expf(lsc[i] - m);
  ss = wredsum(ss);
  if (ln == 0) red[wv] = ss;
  __syncthreads();
  ss = red[0] + red[1] + red[2] + red[3];
  const float logl = __logf(ss);
  __syncthreads();

  const uint32_t jbase = (uint32_t)nt * 1024u + (uint32_t)tid * 4u;
  float ys[4];
  float4 av;
#pragma unroll
  for (int i = 0; i < 4; ++i) {
    float la = lsc[i] - m - logl;
    ((float*)&av)[i] = __expf(la);
    uint32_t o0, o1;
    threefry_0_42(0u, jbase + i, o0, o1);
    uint32_t bits = o0 ^ o1;
    float u = __uint_as_float((bits >> 9) | 0x3f800000u) - 1.0f;
    float g = -__logf(-__logf(u + 1e-20f) + 1e-20f);
    ys[i] = (la + g) * 2.0f;                           // /TEMPERATURE (0.5)
  }
  *(uint2*)(alphaB + (long)nt * 1024 + tid * 4) = pk4(av);

  float m2 = fmaxf(fmaxf(ys[0], ys[1]), fmaxf(ys[2], ys[3]));
  m2 = wredmax(m2);
  if (ln == 0) red[wv] = m2;
  __syncthreads();
  m2 = fmaxf(fmaxf(red[0], red[1]), fmaxf(red[2], red[3]));
  __syncthreads();
  float s2 = 0.f;
  float4 ye;
#pragma unroll
  for (int i = 0; i < 4; ++i) { ((float*)&ye)[i] = __expf(ys[i] - m2); s2 += ((float*)&ye)[i]; }
  s2 = wredsum(s2);
  if (ln == 0) red[wv] = s2;
  __syncthreads();
  s2 = red[0] + red[1] + red[2] + red[3];
  const float rinv = __fdividef(1.f, s2);
  ye.x *= rinv; ye.y *= rinv; ye.z *= rinv; ye.w *= rinv;
  *(uint2*)(yalB + (long)nt * 1024 + tid * 4) = pk4(ye);
}

// ---------------------------------------------------------------- MFMA ctx GEMM
// A = alphaB/yalB bf16 (direct-copy staging); B = mb fp32 strided; out ctxB bf16.
__global__ __launch_bounds__(256) void gemm_ctx_mfma(const unsigned short* __restrict__ alphaB,
                                                     const unsigned short* __restrict__ yalB,
                                                     const float* __restrict__ mb,
                                                     unsigned short* __restrict__ ctxB) {
  __shared__ unsigned short As[64][32];
  const int tid = threadIdx.x;
  const int vt = blockIdx.x >> 4, n = blockIdx.x & 15;
  const int dbase = blockIdx.y * 32;
  const int srow = tid >> 2, kc = tid & 3;
  const int scol = ((kc ^ (srow & 3)) * 8);
  const int wave = tid >> 6, lane = tid & 63;
  const int wm = (wave >> 1) * 32, wn = (wave & 1) * 16;
  const int q = lane >> 4, r = lane & 15;
  const int c0 = ((q ^ (r & 3)) * 8);
  const unsigned short* AB = (vt == 0 ? alphaB : yalB) + (long)n * 65536;
  const unsigned short* apB = AB + (long)srow * 1024 + kc * 8;
  const float* bcol = mb + (long)n * 524288 + dbase + wn + r;  // + s*512
  f32x4 acc[2];
  acc[0] = (f32x4){0.f, 0.f, 0.f, 0.f};
  acc[1] = (f32x4){0.f, 0.f, 0.f, 0.f};

  uint4 fa = *(const uint4*)(apB);
  float bv[8];
#pragma unroll
  for (int j = 0; j < 8; ++j) bv[j] = bcol[(long)(q * 8 + j) * 512];

  for (int k0 = 0; k0 < 1024; k0 += 32) {
    *(uint4*)&As[srow][scol] = fa;
    __syncthreads();
    float4 blo = make_float4(bv[0], bv[1], bv[2], bv[3]);
    float4 bhi = make_float4(bv[4], bv[5], bv[6], bv[7]);
    short8 b0 = mk8(pk4(blo), pk4(bhi));
    if (k0 + 32 < 1024) {
      fa = *(const uint4*)(apB + k0 + 32);
#pragma unroll
      for (int j = 0; j < 8; ++j) bv[j] = bcol[(long)(k0 + 32 + q * 8 + j) * 512];
    }
    short8 a0 = *(const short8*)&As[wm + r][c0];
    short8 a1 = *(const short8*)&As[wm + 16 + r][c0];
    acc[0] = __builtin_amdgcn_mfma_f32_16x16x32_bf16(a0, b0, acc[0], 0, 0, 0);
    acc[1] = __builtin_amdgcn_mfma_f32_16x16x32_bf16(a1, b0, acc[1], 0, 0, 0);
    __syncthreads();
  }
#pragma unroll
  for (int i2 = 0; i2 < 2; ++i2) {
    int gcol = dbase + wn + r;
#pragma unroll
    for (int reg = 0; reg < 4; ++reg) {
      long grow = (long)vt * 1024 + n * 64 + wm + i2 * 16 + q * 4 + reg;
      ctxB[grow * 512 + gcol] = f2bf(acc[i2][reg]);
    }
  }
}

// ---------------------------------------------------------------- fused output GEMM (64x32)
// A = [inputB|ctxB] bf16 direct-copy; B = WoutT. out = tanh(. + b).
__global__ __launch_bounds__(256) void gemm_out_mfma(const unsigned short* __restrict__ inputB,
                                                     const unsigned short* __restrict__ ctxB,
                                                     const unsigned short* __restrict__ WoutT,
                                                     const float* __restrict__ bout,
                                                     float* __restrict__ out) {
  __shared__ unsigned short As[64][32];
  __shared__ unsigned short Bs[32][32];
  const int tid = threadIdx.x;
  const int mbase = blockIdx.x * 64, nbase = blockIdx.y * 32;
  const int srow = tid >> 2, kc = tid & 3;
  const int scol = ((kc ^ (srow & 3)) * 8);
  const int wave = tid >> 6, lane = tid & 63;
  const int wm = (wave >> 1) * 32, wn = (wave & 1) * 16;
  const int q = lane >> 4, r = lane & 15;
  const int c0 = ((q ^ (r & 3)) * 8);
  const int vv = mbase >> 10, nt = (mbase + srow) & 1023;
  const unsigned short* ap_lo = inputB + (long)nt * 512 + kc * 8;
  const unsigned short* ap_hi = ctxB + (long)(vv * 1024 + nt) * 512 + kc * 8 - 512;
  const int brow = (tid & 127) >> 2;                  // 0..31 (tid<128 stages B)
  const unsigned short* bp = WoutT + (long)(nbase + brow) * 1024 + kc * 8;
  f32x4 acc[2];
  acc[0] = (f32x4){0.f, 0.f, 0.f, 0.f};
  acc[1] = (f32x4){0.f, 0.f, 0.f, 0.f};

  uint4 fa = *(const uint4*)(ap_lo);
  uint4 fb;
  if (tid < 128) fb = *(const uint4*)(bp);
  for (int k0 = 0; k0 < 1024; k0 += 32) {
    *(uint4*)&As[srow][scol] = fa;
    if (tid < 128) *(uint4*)&Bs[brow][(kc ^ (brow & 3)) * 8] = fb;
    __syncthreads();
    int kn = k0 + 32;
    if (kn < 1024) {
      const unsigned short* apn = (kn < 512) ? ap_lo : ap_hi;
      fa = *(const uint4*)(apn + kn);
      if (tid < 128) fb = *(const uint4*)(bp + kn);
    }
    short8 a0 = *(const short8*)&As[wm + r][c0];
    short8 a1 = *(const short8*)&As[wm + 16 + r][c0];
    short8 b0 = *(const short8*)&Bs[wn + r][c0];
    acc[0] = __builtin_amdgcn_mfma_f32_16x16x32_bf16(a0, b0, acc[0], 0, 0, 0);
    acc[1] = __builtin_amdgcn_mfma_f32_16x16x32_bf16(a1, b0, acc[1], 0, 0, 0);
    __syncthreads();
  }
#pragma unroll
  for (int i2 = 0; i2 < 2; ++i2) {
    int gcol = nbase + wn + r;
    float bb = bout[gcol];
#pragma unroll
    for (int reg = 0; reg < 4; ++reg) {
      int grow = mbase + wm + i2 * 16 + q * 4 + reg;
      float z = acc[i2][reg] + bb;
      float rc = __builtin_amdgcn_rcpf(1.f + __builtin_amdgcn_exp2f(z * TWO_LOG2E));
      out[(long)grow * 512 + gcol] = fmaf(-2.f, rc, 1.f);
    }
  }
}

// ---------------------------------------------------------------- launch
// ws layout (float units):
//   uhT    [0       , 1048576)  fp32 [16][64][1024] (dead after scores -> ctxB aliases)
//   wq2    [1048576 , 1114112)  fp32 [1024][64]
//   sc     [1114112 , 2162688)  fp32 [1024][1024]
//   alphaB [2162688 , 2686976)  bf16 [1024][1024]
//   yalB   [2686976 , 3211264)  bf16 [1024][1024]
//   inputB [3211264 , 3473408)  bf16 [1024][512]
//   WctxT  [3473408 , 3489792)  bf16 [64][512]
//   WoutT  [3489792 , 3751936)  bf16 [512][1024]
extern "C" void kernel_launch(void* const* d_in, const int* in_sizes, int n_in,
                              void* d_out, int out_size, void* d_ws, size_t ws_size,
                              hipStream_t stream) {
  const float* input = (const float*)d_in[0];   // [16,64,512]
  const float* mb    = (const float*)d_in[1];   // [16,1024,512]
  const float* W_q   = (const float*)d_in[2];   // [512,64]
  const float* W_ctx = (const float*)d_in[3];   // [512,64]
  const float* v     = (const float*)d_in[4];   // [64]
  const float* W_out = (const float*)d_in[5];   // [1024,512]
  const float* b_out = (const float*)d_in[6];   // [512]
  float* out = (float*)d_out;                   // [2,16,64,512]
  float* ws = (float*)d_ws;

  float* uhT   = ws;
  float* wq2   = ws + 1048576;
  float* sc    = ws + 1114112;
  unsigned short* alphaB = (unsigned short*)(ws + 2162688);
  unsigned short* yalB   = (unsigned short*)(ws + 2686976);
  unsigned short* inputB = (unsigned short*)(ws + 3211264);
  unsigned short* WctxT  = (unsigned short*)(ws + 3473408);
  unsigned short* WoutT  = (unsigned short*)(ws + 3489792);
  unsigned short* ctxB   = (unsigned short*)uhT;   // bf16 [2048][512], aliases dead uhT

  prep_kernel<<<168, 256, 0, stream>>>(W_ctx, W_q, W_out, input, WctxT, WoutT, inputB, wq2);
  gemm_uh<<<256, 256, 0, stream>>>(mb, WctxT, uhT);
  scores_tile<<<dim3(16, 4, 16), 256, 0, stream>>>(uhT, wq2, v, sc);
  softmax_gumbel<<<1024, 256, 0, stream>>>(sc, alphaB, yalB);
  gemm_ctx_mfma<<<dim3(32, 16), 256, 0, stream>>>(alphaB, yalB, mb, ctxB);
  gemm_out_mfma<<<dim3(32, 16), 256, 0, stream>>>(inputB, ctxB, WoutT, b_out, out);
}

// Round 12
// 154.081 us; speedup vs baseline: 1.1315x; 1.0092x over previous
//
#include <hip/hip_runtime.h>
#include <hip/hip_bf16.h>
#include <stdint.h>

#define DEV __device__ __forceinline__

typedef __attribute__((ext_vector_type(8))) short short8;   // 8 bf16 (4 VGPRs)
typedef __attribute__((ext_vector_type(4))) float f32x4;    // MFMA acc

#define TWO_LOG2E 2.8853900817779268f   // 2*log2(e): exp(2x) == exp2(x*TWO_LOG2E)

// ---------------------------------------------------------------- helpers
DEV unsigned short f2bf(float f) {           // fp32 -> bf16, RNE
  uint32_t u = __float_as_uint(f);
  u += 0x7FFFu + ((u >> 16) & 1u);
  return (unsigned short)(u >> 16);
}

DEV uint2 pk4(float4 f) {                    // 4 fp32 -> 4 bf16 (packed cvt)
  union { __hip_bfloat162 h; unsigned u; } a, b;
  a.h = __float22bfloat162_rn(make_float2(f.x, f.y));
  b.h = __float22bfloat162_rn(make_float2(f.z, f.w));
  return make_uint2(a.u, b.u);
}

DEV short8 mk8(uint2 lo, uint2 hi) {
  union { short8 s; uint4 u; } t;
  t.u = make_uint4(lo.x, lo.y, hi.x, hi.y);
  return t.s;
}

DEV uint32_t rotl32(uint32_t x, int r) { return (x << r) | (x >> (32 - r)); }

// JAX Threefry-2x32 with key = (0, 42)  (jax.random.key(42))
DEV void threefry_0_42(uint32_t x0, uint32_t x1, uint32_t& o0, uint32_t& o1) {
  const uint32_t ks0 = 0u, ks1 = 42u, ks2 = 0x1BD11BDAu ^ 42u;
  x0 += ks0; x1 += ks1;
#define TFR(r) { x0 += x1; x1 = rotl32(x1, (r)); x1 ^= x0; }
  TFR(13) TFR(15) TFR(26) TFR(6)  x0 += ks1; x1 += ks2 + 1u;
  TFR(17) TFR(29) TFR(16) TFR(24) x0 += ks2; x1 += ks0 + 2u;
  TFR(13) TFR(15) TFR(26) TFR(6)  x0 += ks0; x1 += ks1 + 3u;
  TFR(17) TFR(29) TFR(16) TFR(24) x0 += ks1; x1 += ks2 + 4u;
  TFR(13) TFR(15) TFR(26) TFR(6)  x0 += ks2; x1 += ks0 + 5u;
#undef TFR
  o0 = x0; o1 = x1;
}

DEV float wredmax(float v) {
#pragma unroll
  for (int off = 32; off > 0; off >>= 1) v = fmaxf(v, __shfl_xor(v, off));
  return v;
}
DEV float wredsum(float v) {
#pragma unroll
  for (int off = 32; off > 0; off >>= 1) v += __shfl_xor(v, off);
  return v;
}

// ---------------------------------------------------------------- prep
// blocks 0..127: W_out transpose -> WoutT[512][1024] bf16
// blocks 128..135: W_ctx transpose -> WctxT[64][512] bf16
// blocks 136..151: input -> inputB bf16 (straight cast)
// blocks 152..167: wq2 = TWO_LOG2E*(input @ W_q)  (MFMA, strided B)
__global__ __launch_bounds__(256) void prep_kernel(const float* __restrict__ Wctx,
                                                   const float* __restrict__ Wq,
                                                   const float* __restrict__ Wout,
                                                   const float* __restrict__ input,
                                                   unsigned short* __restrict__ WctxT,
                                                   unsigned short* __restrict__ WoutT,
                                                   unsigned short* __restrict__ inputB,
                                                   float* __restrict__ wq2) {
  const int b = blockIdx.x;
  const int tid = threadIdx.x;
  __shared__ float tile[64][65];
  __shared__ unsigned short As[64][32];
  if (b < 136) {
    const float* src; unsigned short* dst; int R, C, br, bc;
    if (b < 128) { src = Wout; dst = WoutT; R = 1024; C = 512; br = (b & 15) * 64; bc = (b >> 4) * 64; }
    else         { src = Wctx; dst = WctxT; R = 512;  C = 64;  br = (b - 128) * 64; bc = 0; }
    const int lr = tid >> 4, lc4 = (tid & 15) * 4;
#pragma unroll
    for (int i = 0; i < 4; ++i) {
      float4 v = *(const float4*)(src + (long)(br + lr + i * 16) * C + bc + lc4);
      tile[lr + i * 16][lc4 + 0] = v.x;
      tile[lr + i * 16][lc4 + 1] = v.y;
      tile[lr + i * 16][lc4 + 2] = v.z;
      tile[lr + i * 16][lc4 + 3] = v.w;
    }
    __syncthreads();
#pragma unroll
    for (int i = 0; i < 4; ++i) {
      int crow = lr + i * 16;
      ushort4 o;
      o.x = f2bf(tile[lc4 + 0][crow]);
      o.y = f2bf(tile[lc4 + 1][crow]);
      o.z = f2bf(tile[lc4 + 2][crow]);
      o.w = f2bf(tile[lc4 + 3][crow]);
      *(ushort4*)(dst + (long)(bc + crow) * R + br + lc4) = o;
    }
    return;
  }
  if (b < 152) {                               // inputB cast: 32768 elems/block
    const long base = (long)(b - 136) * 32768;
#pragma unroll
    for (int it = 0; it < 32; ++it) {
      long e = base + (it * 256 + tid) * 4;
      float4 f = *(const float4*)(input + e);
      *(uint2*)(inputB + e) = pk4(f);
    }
    return;
  }
  // ---- wq GEMM: 64 rows of input x W_q[512][64] ----
  const int mbase = (b - 152) * 64;
  const int srow = tid >> 2, kc = tid & 3;
  const int scol = ((kc ^ (srow & 3)) * 8);
  const int wave = tid >> 6, lane = tid & 63;
  const int wm = (wave >> 1) * 32, wn = (wave & 1) * 32;
  const int q = lane >> 4, r = lane & 15;
  const int c0 = ((q ^ (r & 3)) * 8);
  const float* ap = input + (long)(mbase + srow) * 512 + kc * 8;
  f32x4 acc[2][2];
#pragma unroll
  for (int i = 0; i < 2; ++i)
#pragma unroll
    for (int j = 0; j < 2; ++j) acc[i][j] = (f32x4){0.f, 0.f, 0.f, 0.f};
  for (int k0 = 0; k0 < 512; k0 += 32) {
    float4 fa0 = *(const float4*)(ap + k0);
    float4 fa1 = *(const float4*)(ap + k0 + 4);
    uint2 p0 = pk4(fa0), p1 = pk4(fa1);
    *(uint4*)&As[srow][scol] = make_uint4(p0.x, p0.y, p1.x, p1.y);
    __syncthreads();
    short8 bfrag[2];
#pragma unroll
    for (int j2 = 0; j2 < 2; ++j2) {
      float bv[8];
#pragma unroll
      for (int j = 0; j < 8; ++j)
        bv[j] = Wq[(long)(k0 + q * 8 + j) * 64 + wn + j2 * 16 + r];
      bfrag[j2] = mk8(pk4(make_float4(bv[0], bv[1], bv[2], bv[3])),
                      pk4(make_float4(bv[4], bv[5], bv[6], bv[7])));
    }
    short8 a0 = *(const short8*)&As[wm + r][c0];
    short8 a1 = *(const short8*)&As[wm + 16 + r][c0];
    acc[0][0] = __builtin_amdgcn_mfma_f32_16x16x32_bf16(a0, bfrag[0], acc[0][0], 0, 0, 0);
    acc[0][1] = __builtin_amdgcn_mfma_f32_16x16x32_bf16(a0, bfrag[1], acc[0][1], 0, 0, 0);
    acc[1][0] = __builtin_amdgcn_mfma_f32_16x16x32_bf16(a1, bfrag[0], acc[1][0], 0, 0, 0);
    acc[1][1] = __builtin_amdgcn_mfma_f32_16x16x32_bf16(a1, bfrag[1], acc[1][1], 0, 0, 0);
    __syncthreads();
  }
#pragma unroll
  for (int i2 = 0; i2 < 2; ++i2)
#pragma unroll
    for (int j2 = 0; j2 < 2; ++j2) {
      int gcol = wn + j2 * 16 + r;
#pragma unroll
      for (int reg = 0; reg < 4; ++reg)
        wq2[(long)(mbase + wm + i2 * 16 + q * 4 + reg) * 64 + gcol] =
            acc[i2][j2][reg] * TWO_LOG2E;
    }
}

// ---------------------------------------------------------------- uh GEMM (transposed out)
// 256 blocks: uhT[n][d][s] = TWO_LOG2E*(mb @ WctxT^T), K=512.
__global__ __launch_bounds__(256) void gemm_uh(const float* __restrict__ mb,
                                               const unsigned short* __restrict__ WctxT,
                                               float* __restrict__ uhT) {
  __shared__ unsigned short As[64][32];
  __shared__ unsigned short Bs[64][32];
  const int tid = threadIdx.x;
  const int mbase = blockIdx.x * 64;
  const int srow = tid >> 2, kc = tid & 3;
  const int scol = ((kc ^ (srow & 3)) * 8);
  const int wave = tid >> 6, lane = tid & 63;
  const int wm = (wave >> 1) * 32, wn = (wave & 1) * 32;
  const int q = lane >> 4, r = lane & 15;
  const int c0 = ((q ^ (r & 3)) * 8);
  const float* ap = mb + (long)(mbase + srow) * 512 + kc * 8;
  const unsigned short* bp = WctxT + (long)srow * 512 + kc * 8;
  f32x4 acc[2][2];
#pragma unroll
  for (int i = 0; i < 2; ++i)
#pragma unroll
    for (int j = 0; j < 2; ++j) acc[i][j] = (f32x4){0.f, 0.f, 0.f, 0.f};

  float4 fa0 = *(const float4*)(ap);
  float4 fa1 = *(const float4*)(ap + 4);
  uint4 fb = *(const uint4*)(bp);
  for (int k0 = 0; k0 < 512; k0 += 32) {
    uint2 p0 = pk4(fa0), p1 = pk4(fa1);
    *(uint4*)&As[srow][scol] = make_uint4(p0.x, p0.y, p1.x, p1.y);
    *(uint4*)&Bs[srow][scol] = fb;
    __syncthreads();
    if (k0 + 32 < 512) {
      fa0 = *(const float4*)(ap + k0 + 32);
      fa1 = *(const float4*)(ap + k0 + 36);
      fb = *(const uint4*)(bp + k0 + 32);
    }
    short8 a0 = *(const short8*)&As[wm + r][c0];
    short8 a1 = *(const short8*)&As[wm + 16 + r][c0];
    short8 b0 = *(const short8*)&Bs[wn + r][c0];
    short8 b1 = *(const short8*)&Bs[wn + 16 + r][c0];
    acc[0][0] = __builtin_amdgcn_mfma_f32_16x16x32_bf16(a0, b0, acc[0][0], 0, 0, 0);
    acc[0][1] = __builtin_amdgcn_mfma_f32_16x16x32_bf16(a0, b1, acc[0][1], 0, 0, 0);
    acc[1][0] = __builtin_amdgcn_mfma_f32_16x16x32_bf16(a1, b0, acc[1][0], 0, 0, 0);
    acc[1][1] = __builtin_amdgcn_mfma_f32_16x16x32_bf16(a1, b1, acc[1][1], 0, 0, 0);
    __syncthreads();
  }
#pragma unroll
  for (int i2 = 0; i2 < 2; ++i2)
#pragma unroll
    for (int j2 = 0; j2 < 2; ++j2) {
      int gcol = wn + j2 * 16 + r;                      // d
      int m = mbase + wm + i2 * 16 + q * 4;             // n*1024 + s (4 consecutive via reg)
      int n = m >> 10, s0 = m & 1023;
      float4 o;
      o.x = acc[i2][j2][0] * TWO_LOG2E;
      o.y = acc[i2][j2][1] * TWO_LOG2E;
      o.z = acc[i2][j2][2] * TWO_LOG2E;
      o.w = acc[i2][j2][3] * TWO_LOG2E;
      *(float4*)(uhT + (long)n * 65536 + (long)gcol * 1024 + s0) = o;
    }
}

// ---------------------------------------------------------------- fused scores + softmax + gumbel
// 1024 blocks, one per nt. Thread owns 4 CONSECUTIVE s (s0 = 4*tid); every uhT load
// is wave-contiguous (L2-resident re-reads). wq2/v via LDS broadcast. Outputs bf16.
__global__ __launch_bounds__(256) void scores_softmax(const float* __restrict__ uhT,
                                                      const float* __restrict__ wq2,
                                                      const float* __restrict__ v,
                                                      unsigned short* __restrict__ alphaB,
                                                      unsigned short* __restrict__ yalB) {
  const int tid = threadIdx.x;
  const int nt = blockIdx.x;           // n*64 + t
  const int n = nt >> 6;
  __shared__ float wvs[64];
  __shared__ float vvs[64];
  __shared__ float red[4];
  if (tid < 64) {
    wvs[tid] = wq2[nt * 64 + tid];
    vvs[tid] = v[tid];
  }
  __syncthreads();

  float sumv = 0.f;
#pragma unroll
  for (int d = 0; d < 64; d += 4) {
    float4 vv = *(const float4*)&vvs[d];
    sumv += vv.x + vv.y + vv.z + vv.w;
  }

  const float* un = uhT + (long)n * 65536 + tid * 4;   // + d*1024
  float4 racc = make_float4(0.f, 0.f, 0.f, 0.f);
  for (int db = 0; db < 64; db += 8) {
    float4 ub[8];
#pragma unroll
    for (int j = 0; j < 8; ++j) ub[j] = *(const float4*)(un + (long)(db + j) * 1024);
#pragma unroll
    for (int j = 0; j < 8; ++j) {
      float w = wvs[db + j], vvj = vvs[db + j];
      racc.x = fmaf(vvj, __builtin_amdgcn_rcpf(1.f + __builtin_amdgcn_exp2f(ub[j].x + w)), racc.x);
      racc.y = fmaf(vvj, __builtin_amdgcn_rcpf(1.f + __builtin_amdgcn_exp2f(ub[j].y + w)), racc.y);
      racc.z = fmaf(vvj, __builtin_amdgcn_rcpf(1.f + __builtin_amdgcn_exp2f(ub[j].z + w)), racc.z);
      racc.w = fmaf(vvj, __builtin_amdgcn_rcpf(1.f + __builtin_amdgcn_exp2f(ub[j].w + w)), racc.w);
    }
  }
  float lsc[4];
  lsc[0] = fmaf(-2.f, racc.x, sumv);
  lsc[1] = fmaf(-2.f, racc.y, sumv);
  lsc[2] = fmaf(-2.f, racc.z, sumv);
  lsc[3] = fmaf(-2.f, racc.w, sumv);

  // ---- log_softmax over S=1024 ----
  const int wv = tid >> 6, ln = tid & 63;
  float m = fmaxf(fmaxf(lsc[0], lsc[1]), fmaxf(lsc[2], lsc[3]));
  m = wredmax(m);
  if (ln == 0) red[wv] = m;
  __syncthreads();
  m = fmaxf(fmaxf(red[0], red[1]), fmaxf(red[2], red[3]));
  __syncthreads();
  float ss = 0.f;
#pragma unroll
  for (int i = 0; i < 4; ++i) ss += __expf(lsc[i] - m);
  ss = wredsum(ss);
  if (ln == 0) red[wv] = ss;
  __syncthreads();
  ss = red[0] + red[1] + red[2] + red[3];
  const float logl = __logf(ss);
  __syncthreads();

  // ---- alpha + gumbel (JAX partitionable threefry, key=(0,42); bits = o0^o1) ----
  const uint32_t jbase = (uint32_t)nt * 1024u + (uint32_t)tid * 4u;
  float ys[4];
  float4 av;
#pragma unroll
  for (int i = 0; i < 4; ++i) {
    float la = lsc[i] - m - logl;
    ((float*)&av)[i] = __expf(la);
    uint32_t o0, o1;
    threefry_0_42(0u, jbase + i, o0, o1);
    uint32_t bits = o0 ^ o1;
    float u = __uint_as_float((bits >> 9) | 0x3f800000u) - 1.0f;
    float g = -__logf(-__logf(u + 1e-20f) + 1e-20f);
    ys[i] = (la + g) * 2.0f;                           // /TEMPERATURE (0.5)
  }
  *(uint2*)(alphaB + (long)nt * 1024 + tid * 4) = pk4(av);

  // ---- softmax over ys ----
  float m2 = fmaxf(fmaxf(ys[0], ys[1]), fmaxf(ys[2], ys[3]));
  m2 = wredmax(m2);
  if (ln == 0) red[wv] = m2;
  __syncthreads();
  m2 = fmaxf(fmaxf(red[0], red[1]), fmaxf(red[2], red[3]));
  __syncthreads();
  float s2 = 0.f;
  float4 ye;
#pragma unroll
  for (int i = 0; i < 4; ++i) { ((float*)&ye)[i] = __expf(ys[i] - m2); s2 += ((float*)&ye)[i]; }
  s2 = wredsum(s2);
  if (ln == 0) red[wv] = s2;
  __syncthreads();
  s2 = red[0] + red[1] + red[2] + red[3];
  const float rinv = __fdividef(1.f, s2);
  ye.x *= rinv; ye.y *= rinv; ye.z *= rinv; ye.w *= rinv;
  *(uint2*)(yalB + (long)nt * 1024 + tid * 4) = pk4(ye);
}

// ---------------------------------------------------------------- MFMA ctx GEMM
// A = alphaB/yalB bf16 (direct-copy staging); B = mb fp32 strided; out ctxB bf16.
__global__ __launch_bounds__(256) void gemm_ctx_mfma(const unsigned short* __restrict__ alphaB,
                                                     const unsigned short* __restrict__ yalB,
                                                     const float* __restrict__ mb,
                                                     unsigned short* __restrict__ ctxB) {
  __shared__ unsigned short As[64][32];
  const int tid = threadIdx.x;
  const int vt = blockIdx.x >> 4, n = blockIdx.x & 15;
  const int dbase = blockIdx.y * 32;
  const int srow = tid >> 2, kc = tid & 3;
  const int scol = ((kc ^ (srow & 3)) * 8);
  const int wave = tid >> 6, lane = tid & 63;
  const int wm = (wave >> 1) * 32, wn = (wave & 1) * 16;
  const int q = lane >> 4, r = lane & 15;
  const int c0 = ((q ^ (r & 3)) * 8);
  const unsigned short* AB = (vt == 0 ? alphaB : yalB) + (long)n * 65536;
  const unsigned short* apB = AB + (long)srow * 1024 + kc * 8;
  const float* bcol = mb + (long)n * 524288 + dbase + wn + r;  // + s*512
  f32x4 acc[2];
  acc[0] = (f32x4){0.f, 0.f, 0.f, 0.f};
  acc[1] = (f32x4){0.f, 0.f, 0.f, 0.f};

  uint4 fa = *(const uint4*)(apB);
  float bv[8];
#pragma unroll
  for (int j = 0; j < 8; ++j) bv[j] = bcol[(long)(q * 8 + j) * 512];

  for (int k0 = 0; k0 < 1024; k0 += 32) {
    *(uint4*)&As[srow][scol] = fa;
    __syncthreads();
    float4 blo = make_float4(bv[0], bv[1], bv[2], bv[3]);
    float4 bhi = make_float4(bv[4], bv[5], bv[6], bv[7]);
    short8 b0 = mk8(pk4(blo), pk4(bhi));
    if (k0 + 32 < 1024) {
      fa = *(const uint4*)(apB + k0 + 32);
#pragma unroll
      for (int j = 0; j < 8; ++j) bv[j] = bcol[(long)(k0 + 32 + q * 8 + j) * 512];
    }
    short8 a0 = *(const short8*)&As[wm + r][c0];
    short8 a1 = *(const short8*)&As[wm + 16 + r][c0];
    acc[0] = __builtin_amdgcn_mfma_f32_16x16x32_bf16(a0, b0, acc[0], 0, 0, 0);
    acc[1] = __builtin_amdgcn_mfma_f32_16x16x32_bf16(a1, b0, acc[1], 0, 0, 0);
    __syncthreads();
  }
#pragma unroll
  for (int i2 = 0; i2 < 2; ++i2) {
    int gcol = dbase + wn + r;
#pragma unroll
    for (int reg = 0; reg < 4; ++reg) {
      long grow = (long)vt * 1024 + n * 64 + wm + i2 * 16 + q * 4 + reg;
      ctxB[grow * 512 + gcol] = f2bf(acc[i2][reg]);
    }
  }
}

// ---------------------------------------------------------------- fused output GEMM (64x32)
// A = [inputB|ctxB] bf16 direct-copy; B = WoutT. out = tanh(. + b).
__global__ __launch_bounds__(256) void gemm_out_mfma(const unsigned short* __restrict__ inputB,
                                                     const unsigned short* __restrict__ ctxB,
                                                     const unsigned short* __restrict__ WoutT,
                                                     const float* __restrict__ bout,
                                                     float* __restrict__ out) {
  __shared__ unsigned short As[64][32];
  __shared__ unsigned short Bs[32][32];
  const int tid = threadIdx.x;
  const int mbase = blockIdx.x * 64, nbase = blockIdx.y * 32;
  const int srow = tid >> 2, kc = tid & 3;
  const int scol = ((kc ^ (srow & 3)) * 8);
  const int wave = tid >> 6, lane = tid & 63;
  const int wm = (wave >> 1) * 32, wn = (wave & 1) * 16;
  const int q = lane >> 4, r = lane & 15;
  const int c0 = ((q ^ (r & 3)) * 8);
  const int vv = mbase >> 10, nt = (mbase + srow) & 1023;
  const unsigned short* ap_lo = inputB + (long)nt * 512 + kc * 8;
  const unsigned short* ap_hi = ctxB + (long)(vv * 1024 + nt) * 512 + kc * 8 - 512;
  const int brow = (tid & 127) >> 2;                  // 0..31 (tid<128 stages B)
  const unsigned short* bp = WoutT + (long)(nbase + brow) * 1024 + kc * 8;
  f32x4 acc[2];
  acc[0] = (f32x4){0.f, 0.f, 0.f, 0.f};
  acc[1] = (f32x4){0.f, 0.f, 0.f, 0.f};

  uint4 fa = *(const uint4*)(ap_lo);
  uint4 fb;
  if (tid < 128) fb = *(const uint4*)(bp);
  for (int k0 = 0; k0 < 1024; k0 += 32) {
    *(uint4*)&As[srow][scol] = fa;
    if (tid < 128) *(uint4*)&Bs[brow][(kc ^ (brow & 3)) * 8] = fb;
    __syncthreads();
    int kn = k0 + 32;
    if (kn < 1024) {
      const unsigned short* apn = (kn < 512) ? ap_lo : ap_hi;
      fa = *(const uint4*)(apn + kn);
      if (tid < 128) fb = *(const uint4*)(bp + kn);
    }
    short8 a0 = *(const short8*)&As[wm + r][c0];
    short8 a1 = *(const short8*)&As[wm + 16 + r][c0];
    short8 b0 = *(const short8*)&Bs[wn + r][c0];
    acc[0] = __builtin_amdgcn_mfma_f32_16x16x32_bf16(a0, b0, acc[0], 0, 0, 0);
    acc[1] = __builtin_amdgcn_mfma_f32_16x16x32_bf16(a1, b0, acc[1], 0, 0, 0);
    __syncthreads();
  }
#pragma unroll
  for (int i2 = 0; i2 < 2; ++i2) {
    int gcol = nbase + wn + r;
    float bb = bout[gcol];
#pragma unroll
    for (int reg = 0; reg < 4; ++reg) {
      int grow = mbase + wm + i2 * 16 + q * 4 + reg;
      float z = acc[i2][reg] + bb;
      float rc = __builtin_amdgcn_rcpf(1.f + __builtin_amdgcn_exp2f(z * TWO_LOG2E));
      out[(long)grow * 512 + gcol] = fmaf(-2.f, rc, 1.f);
    }
  }
}

// ---------------------------------------------------------------- launch
// ws layout (float units):
//   uhT    [0       , 1048576)  fp32 [16][64][1024] (dead after scores -> ctxB aliases)
//   wq2    [1048576 , 1114112)  fp32 [1024][64]
//   alphaB [1114112 , 1638400)  bf16 [1024][1024]
//   yalB   [1638400 , 2162688)  bf16 [1024][1024]
//   inputB [2162688 , 2424832)  bf16 [1024][512]
//   WctxT  [2424832 , 2441216)  bf16 [64][512]
//   WoutT  [2441216 , 2703360)  bf16 [512][1024]
extern "C" void kernel_launch(void* const* d_in, const int* in_sizes, int n_in,
                              void* d_out, int out_size, void* d_ws, size_t ws_size,
                              hipStream_t stream) {
  const float* input = (const float*)d_in[0];   // [16,64,512]
  const float* mb    = (const float*)d_in[1];   // [16,1024,512]
  const float* W_q   = (const float*)d_in[2];   // [512,64]
  const float* W_ctx = (const float*)d_in[3];   // [512,64]
  const float* v     = (const float*)d_in[4];   // [64]
  const float* W_out = (const float*)d_in[5];   // [1024,512]
  const float* b_out = (const float*)d_in[6];   // [512]
  float* out = (float*)d_out;                   // [2,16,64,512]
  float* ws = (float*)d_ws;

  float* uhT   = ws;
  float* wq2   = ws + 1048576;
  unsigned short* alphaB = (unsigned short*)(ws + 1114112);
  unsigned short* yalB   = (unsigned short*)(ws + 1638400);
  unsigned short* inputB = (unsigned short*)(ws + 2162688);
  unsigned short* WctxT  = (unsigned short*)(ws + 2424832);
  unsigned short* WoutT  = (unsigned short*)(ws + 2441216);
  unsigned short* ctxB   = (unsigned short*)uhT;   // bf16 [2048][512], aliases dead uhT

  prep_kernel<<<168, 256, 0, stream>>>(W_ctx, W_q, W_out, input, WctxT, WoutT, inputB, wq2);
  gemm_uh<<<256, 256, 0, stream>>>(mb, WctxT, uhT);
  scores_softmax<<<1024, 256, 0, stream>>>(uhT, wq2, v, alphaB, yalB);
  gemm_ctx_mfma<<<dim3(32, 16), 256, 0, stream>>>(alphaB, yalB, mb, ctxB);
  gemm_out_mfma<<<dim3(32, 16), 256, 0, stream>>>(inputB, ctxB, WoutT, b_out, out);
}